// Round 3
// baseline (2115.010 us; speedup 1.0000x reference)
//
#include <hip/hip_runtime.h>
#include <hip/hip_cooperative_groups.h>

namespace cg = cooperative_groups;

// ---------------- problem constants ----------------
constexpr int B_ = 8, T_ = 256, H_ = 64, L_ = 3, NB_ = 17, NF_ = 68, HP_ = 6, K_ = 9;
constexpr int FEAT_DIM = NB_ * H_ + NF_ * H_ + H_;   // 5504
constexpr int HT = H_ * T_;                          // 16384 per (b,n)

typedef _Float16 half4_t __attribute__((ext_vector_type(4)));
typedef _Float16 half8_t __attribute__((ext_vector_type(8)));
typedef float f32x16 __attribute__((ext_vector_type(16)));
typedef float f32x4 __attribute__((ext_vector_type(4)));

// ---------------- workspace layout (float units); activations f16 [bn][t][o] ----------------
constexpr size_t SZ_AB = (size_t)B_ * NB_ * HT;
constexpr size_t SZ_AF = (size_t)B_ * NF_ * HT;
constexpr size_t OFF_TB   = 0;
constexpr size_t OFF_TF   = OFF_TB + SZ_AB / 2;
constexpr size_t OFF_SUPB = OFF_TF + SZ_AF / 2;
constexpr size_t OFF_SUPF = OFF_SUPB + SZ_AB / 2;
constexpr size_t OFF_GB   = OFF_SUPF + SZ_AF / 2;
constexpr size_t OFF_GF   = OFF_GB + SZ_AB / 2;
constexpr size_t OFF_W3   = OFF_GF + SZ_AF / 2;      // 4 conv sets x 110592 f16
constexpr size_t OFF_GW3  = OFF_W3 + 4 * 55296;      // 2 x 12288 f16
constexpr size_t OFF_B2   = OFF_GW3 + 2 * 6144;      // 4 x 192 f32
constexpr size_t OFF_ADJPB= OFF_B2 + 768;            // 32x32 f16
constexpr size_t OFF_ADJPF= OFF_ADJPB + 512;         // 96x80 f16
constexpr size_t OFF_FEAT = OFF_ADJPF + 3840;        // 8x5504 f32
constexpr size_t OFF_P1   = OFF_FEAT + (size_t)B_ * FEAT_DIM;

struct ConvPrepSet { const float *w, *tb, *g, *bb, *m, *v; };

// ---------------- all pointers in one arg struct ----------------
struct Args {
    const float *body_kps, *face_kps, *head_pose, *body_adj, *face_adj;
    const float *body_pw, *body_pb, *face_pw, *face_pb, *head_w, *head_b;
    ConvPrepSet sb1, sb2, sf1, sf2;
    const float *b_gcw, *f_gcw, *b_gcb, *f_gcb;
    const float *fus1_w, *fus1_b, *fus2_w, *fus2_b, *fus3_w, *fus3_b, *fus4_w, *fus4_b;
    _Float16 *TrB, *TrF, *SupB, *SupF, *Gb, *Gf;
    _Float16 *W3, *GW3, *adjPB, *adjPF;
    float *B2, *p1, *feat;
    float *out;
};

// ---------------- small helpers ----------------
__device__ __forceinline__ half8_t ld_b8(const _Float16* p) {
    half4_t lo = *(const half4_t*)p;
    half4_t hi = *(const half4_t*)(p + 4);
    return __builtin_shufflevector(lo, hi, 0, 1, 2, 3, 4, 5, 6, 7);
}

__device__ __forceinline__ void st_b8(_Float16* p, half8_t v) {
    half4_t lo, hi;
#pragma unroll
    for (int j = 0; j < 4; ++j) { lo[j] = v[j]; hi[j] = v[4 + j]; }
    *(half4_t*)p = lo;
    *(half4_t*)(p + 4) = hi;
}

// stage f16 [t][o] (contiguous 128B rows) -> Xs[t+4][c], pitch 68; rows 0..263 = t -4..259
__device__ __forceinline__ void stage_full(const _Float16* __restrict__ xb,
                                           _Float16* __restrict__ Xs, int tid) {
    for (int u = tid; u < 264 * 8; u += 256) {
        int row = u >> 3, c = u & 7;
        int t = row - 4;
        half8_t v;
        if (t >= 0 && t < T_) {
            v = *(const half8_t*)(xb + (size_t)t * H_ + c * 8);
        } else {
#pragma unroll
            for (int j = 0; j < 8; ++j) v[j] = (_Float16)0.f;
        }
        st_b8(&Xs[row * 68 + c * 8], v);
    }
}

// stage residual trunk rows [t][o] -> Rs[t][c], pitch 68 (t = 0..255)
__device__ __forceinline__ void stage_res(const _Float16* __restrict__ xb,
                                          _Float16* __restrict__ Rs, int tid) {
    for (int u = tid; u < 256 * 8; u += 256) {
        int row = u >> 3, c = u & 7;
        half8_t v = *(const half8_t*)(xb + (size_t)row * H_ + c * 8);
        st_b8(&Rs[row * 68 + c * 8], v);
    }
}

// ---------------- phase units ----------------

// prep: fold BN into conv W; gcw pack; adj pad; zero p1/feat (skip head cols: proj writes them)
__device__ void prep_unit(const Args& A, int blk, int tid) {
    if (blk < 1728) {                       // conv-weight fold: 4 sets x 432 blocks
        int set = blk / 432;
        int bx = blk % 432;
        ConvPrepSet s = (set == 0) ? A.sb1 : (set == 1) ? A.sb2 : (set == 2) ? A.sf1 : A.sf2;
        int idx = bx * 256 + tid;           // < 110592
        int k = idx % K_; int r = idx / K_;
        int i = r % H_; r /= H_;
        int o = r % H_; int l = r / H_;
        float sc = s.g[l * H_ + o] * rsqrtf(s.v[l * H_ + o] + 1e-5f);
        A.W3[(size_t)set * 110592 + ((((l * K_ + k) * 8 + (i >> 3)) * H_ + o) * 8) + (i & 7)]
            = (_Float16)(s.w[idx] * sc);
        if (i == 0 && k == 0)
            A.B2[set * 192 + l * H_ + o] =
                s.tb[l * H_ + o] * sc + s.bb[l * H_ + o] - s.m[l * H_ + o] * sc;
    } else if (blk < 1824) {                // gc-weight pack: 2 sets x 48 blocks
        int set = (blk - 1728) / 48;
        int bx = (blk - 1728) % 48;
        const float* gw = set ? A.f_gcw : A.b_gcw;
        int idx = bx * 256 + tid;           // < 12288
        int o = idx % H_; int r = idx / H_;
        int c = r % H_; int l = r / H_;
        A.GW3[(size_t)set * 12288 + (((l * 8 + (c >> 3)) * H_ + o) * 8) + (c & 7)]
            = (_Float16)gw[idx];
    } else {                                // misc: adj pad + zero p1/feat
        int idx = (blk - 1824) * 256 + tid;
        if (idx < 1024) {
            int m = idx >> 5, k = idx & 31;
            A.adjPB[idx] = (m < NB_ && k < NB_) ? (_Float16)A.body_adj[m * NB_ + k] : (_Float16)0.f;
        } else if (idx < 8704) {
            int j = idx - 1024;
            int m = j / 80, k = j % 80;
            A.adjPF[j] = (m < NF_ && k < NF_) ? (_Float16)A.face_adj[m * NF_ + k] : (_Float16)0.f;
        } else if (idx < 10752) {
            A.p1[idx - 8704] = 0.f;
        } else if (idx < 10752 + B_ * FEAT_DIM) {
            int j = idx - 10752;
            if (j % FEAT_DIM < NB_ * H_ + NF_ * H_)   // head cols written by head_unit
                A.feat[j] = 0.f;
        }
    }
}

// projection -> trunk f16 [bn][t][o]
__device__ void proj_unit(const Args& A, int u, int tid) {
    const float *kps, *pw, *pb; _Float16* out; int N, bn;
    if (u < B_ * NB_) { kps = A.body_kps; pw = A.body_pw; pb = A.body_pb; out = A.TrB; N = NB_; bn = u; }
    else { kps = A.face_kps; pw = A.face_pw; pb = A.face_pb; out = A.TrF; N = NF_; bn = u - B_ * NB_; }
    int b = bn / N, n = bn % N;
    int t = tid;
    float x0 = kps[((size_t)b * T_ + t) * (N * 2) + n * 2 + 0];
    float x1 = kps[((size_t)b * T_ + t) * (N * 2) + n * 2 + 1];
    _Float16* ob = out + (size_t)bn * HT + (size_t)t * H_;
#pragma unroll
    for (int cg2 = 0; cg2 < 8; ++cg2) {
        half8_t v;
#pragma unroll
        for (int j = 0; j < 8; ++j) {
            int c = cg2 * 8 + j;
            v[j] = (_Float16)fmaf(x0, pw[c], fmaf(x1, pw[H_ + c], pb[c]));
        }
        *(half8_t*)(ob + cg2 * 8) = v;
    }
}

// head stream: relu(head_pose @ head_w + head_b).mean(t) -> feat tail (NO early return)
__device__ void head_unit(const Args& A, int b, int tid) {
    if (tid < 64) {
        int c = tid;
        float w0 = A.head_w[c], w1 = A.head_w[64 + c], w2 = A.head_w[128 + c],
              w3 = A.head_w[192 + c], w4 = A.head_w[256 + c], w5 = A.head_w[320 + c];
        float bias = A.head_b[c];
        float acc = 0.f;
        for (int t = 0; t < T_; ++t) {
            const float* xr = A.head_pose + ((size_t)b * T_ + t) * HP_;
            float s = fmaf(xr[0], w0, fmaf(xr[1], w1, fmaf(xr[2], w2,
                      fmaf(xr[3], w3, fmaf(xr[4], w4, fmaf(xr[5], w5, bias))))));
            acc += fmaxf(s, 0.f);
        }
        A.feat[(size_t)b * FEAT_DIM + NB_ * H_ + NF_ * H_ + c] = acc * (1.f / 256.f);
    }
}

// fused conv1(+bn+relu)+channel-mix : trunk f16 -> support f16 (one bn, full T)
__device__ void convmix_unit(const _Float16* __restrict__ x,
                             const half8_t* __restrict__ w1,
                             const float* __restrict__ b1,
                             const half8_t* __restrict__ gc,
                             _Float16* __restrict__ sup,
                             int bn, int l, _Float16* __restrict__ Xs, int tid) {
    stage_full(x + (size_t)bn * HT, Xs, tid);
    __syncthreads();

    int ln = tid & 63;
    int w = __builtin_amdgcn_readfirstlane(tid >> 6);
    int ln31 = ln & 31, kg = ln >> 5;
    int tw = w * 64;

    f32x16 acc[2][2];   // [o-tile][t-frag]
#pragma unroll
    for (int mt = 0; mt < 2; ++mt)
#pragma unroll
        for (int f = 0; f < 2; ++f)
#pragma unroll
            for (int r = 0; r < 16; ++r) acc[mt][f][r] = 0.f;

    const half8_t* wl = w1 + (size_t)l * (K_ * 8 * H_);
    const _Float16* xr0 = Xs + (size_t)(tw + ln31) * 68;
#pragma unroll
    for (int tap = 0; tap < K_; ++tap) {
#pragma unroll
        for (int ks = 0; ks < 4; ++ks) {
            int i8 = ks * 2 + kg;
            half8_t a0 = wl[(tap * 8 + i8) * H_ + ln31];
            half8_t a1 = wl[(tap * 8 + i8) * H_ + 32 + ln31];
            half8_t b0 = ld_b8(xr0 + tap * 68 + i8 * 8);
            half8_t b1v = ld_b8(xr0 + (32 + tap) * 68 + i8 * 8);
            acc[0][0] = __builtin_amdgcn_mfma_f32_32x32x16_f16(a0, b0, acc[0][0], 0, 0, 0);
            acc[0][1] = __builtin_amdgcn_mfma_f32_32x32x16_f16(a0, b1v, acc[0][1], 0, 0, 0);
            acc[1][0] = __builtin_amdgcn_mfma_f32_32x32x16_f16(a1, b0, acc[1][0], 0, 0, 0);
            acc[1][1] = __builtin_amdgcn_mfma_f32_32x32x16_f16(a1, b1v, acc[1][1], 0, 0, 0);
        }
    }
    __syncthreads();

    // conv1 epilogue: bias+relu -> mid row Xs[4+t][o]
#pragma unroll
    for (int f = 0; f < 2; ++f) {
        _Float16* mrow = Xs + (size_t)(4 + tw + f * 32 + ln31) * 68;
#pragma unroll
        for (int mt = 0; mt < 2; ++mt) {
#pragma unroll
            for (int rg = 0; rg < 4; ++rg) {
                int o0 = mt * 32 + rg * 8 + kg * 4;
                f32x4 bv = *(const f32x4*)(b1 + l * H_ + o0);
                half4_t hv;
#pragma unroll
                for (int j = 0; j < 4; ++j)
                    hv[j] = (_Float16)fmaxf(acc[mt][f][rg * 4 + j] + bv[j], 0.f);
                *(half4_t*)(mrow + o0) = hv;
            }
        }
    }
    __syncthreads();

    // channel mix (K=64)
    f32x16 acc2[2][2];
#pragma unroll
    for (int mt = 0; mt < 2; ++mt)
#pragma unroll
        for (int f = 0; f < 2; ++f)
#pragma unroll
            for (int r = 0; r < 16; ++r) acc2[mt][f][r] = 0.f;
    const half8_t* gl = gc + (size_t)l * (8 * H_);
    const _Float16* mrow0 = Xs + (size_t)(4 + tw + ln31) * 68;
#pragma unroll
    for (int ks = 0; ks < 4; ++ks) {
        int i8 = ks * 2 + kg;
        half8_t a0 = gl[i8 * H_ + ln31];
        half8_t a1 = gl[i8 * H_ + 32 + ln31];
        half8_t b0 = ld_b8(mrow0 + i8 * 8);
        half8_t b1v = ld_b8(mrow0 + 32 * 68 + i8 * 8);
        acc2[0][0] = __builtin_amdgcn_mfma_f32_32x32x16_f16(a0, b0, acc2[0][0], 0, 0, 0);
        acc2[0][1] = __builtin_amdgcn_mfma_f32_32x32x16_f16(a0, b1v, acc2[0][1], 0, 0, 0);
        acc2[1][0] = __builtin_amdgcn_mfma_f32_32x32x16_f16(a1, b0, acc2[1][0], 0, 0, 0);
        acc2[1][1] = __builtin_amdgcn_mfma_f32_32x32x16_f16(a1, b1v, acc2[1][1], 0, 0, 0);
    }

    // write acc2 -> Xs[4+t][o] (wave-own rows), then coalesced b128 copy-out
#pragma unroll
    for (int f = 0; f < 2; ++f) {
        _Float16* orow = Xs + (size_t)(4 + tw + f * 32 + ln31) * 68;
#pragma unroll
        for (int mt = 0; mt < 2; ++mt) {
#pragma unroll
            for (int rg = 0; rg < 4; ++rg) {
                int o0 = mt * 32 + rg * 8 + kg * 4;
                half4_t hv;
#pragma unroll
                for (int j = 0; j < 4; ++j)
                    hv[j] = (_Float16)acc2[mt][f][rg * 4 + j];
                *(half4_t*)(orow + o0) = hv;
            }
        }
    }
    __syncthreads();
    _Float16* gout = sup + (size_t)bn * HT + (size_t)tw * H_;
    const _Float16* srow = Xs + (size_t)(4 + tw) * 68;
#pragma unroll
    for (int k2 = 0; k2 < 8; ++k2) {
        int u = k2 * 64 + ln;
        int r = u >> 3, c = u & 7;
        half8_t v = ld_b8(srow + r * 68 + c * 8);
        *(half8_t*)(gout + (size_t)r * H_ + c * 8) = v;
    }
}

// conv2(+bn)+residual : G f16 -> trunk f16; LAST: mean-pool -> feat
template <bool LAST>
__device__ void conv2_unit(const _Float16* __restrict__ x,
                           const half8_t* __restrict__ w2,
                           const float* __restrict__ b2,
                           _Float16* __restrict__ trunk,
                           int N, int fbase, int bn, int l,
                           float* __restrict__ feat,
                           _Float16* __restrict__ Xs, _Float16* __restrict__ Rs, int tid) {
    stage_full(x + (size_t)bn * HT, Xs, tid);
    stage_res(trunk + (size_t)bn * HT, Rs, tid);
    __syncthreads();

    int ln = tid & 63;
    int w = __builtin_amdgcn_readfirstlane(tid >> 6);
    int ln31 = ln & 31, kg = ln >> 5;
    int tw = w * 64;

    f32x16 acc[2][2];
#pragma unroll
    for (int mt = 0; mt < 2; ++mt)
#pragma unroll
        for (int f = 0; f < 2; ++f)
#pragma unroll
            for (int r = 0; r < 16; ++r) acc[mt][f][r] = 0.f;

    const half8_t* wl = w2 + (size_t)l * (K_ * 8 * H_);
    const _Float16* xr0 = Xs + (size_t)(tw + ln31) * 68;
#pragma unroll
    for (int tap = 0; tap < K_; ++tap) {
#pragma unroll
        for (int ks = 0; ks < 4; ++ks) {
            int i8 = ks * 2 + kg;
            half8_t a0 = wl[(tap * 8 + i8) * H_ + ln31];
            half8_t a1 = wl[(tap * 8 + i8) * H_ + 32 + ln31];
            half8_t b0 = ld_b8(xr0 + tap * 68 + i8 * 8);
            half8_t b1v = ld_b8(xr0 + (32 + tap) * 68 + i8 * 8);
            acc[0][0] = __builtin_amdgcn_mfma_f32_32x32x16_f16(a0, b0, acc[0][0], 0, 0, 0);
            acc[0][1] = __builtin_amdgcn_mfma_f32_32x32x16_f16(a0, b1v, acc[0][1], 0, 0, 0);
            acc[1][0] = __builtin_amdgcn_mfma_f32_32x32x16_f16(a1, b0, acc[1][0], 0, 0, 0);
            acc[1][1] = __builtin_amdgcn_mfma_f32_32x32x16_f16(a1, b1v, acc[1][1], 0, 0, 0);
        }
    }

    if (!LAST) {
        __syncthreads();   // all conv B-reads done before overwriting Xs rows
#pragma unroll
        for (int f = 0; f < 2; ++f) {
            int row = tw + f * 32 + ln31;
            _Float16* orow = Xs + (size_t)(4 + row) * 68;
            const _Float16* rrow = Rs + (size_t)row * 68;
#pragma unroll
            for (int mt = 0; mt < 2; ++mt) {
#pragma unroll
                for (int rg = 0; rg < 4; ++rg) {
                    int o0 = mt * 32 + rg * 8 + kg * 4;
                    f32x4 bv = *(const f32x4*)(b2 + l * H_ + o0);
                    half4_t rv = *(const half4_t*)(rrow + o0);
                    half4_t hv;
#pragma unroll
                    for (int j = 0; j < 4; ++j)
                        hv[j] = (_Float16)(acc[mt][f][rg * 4 + j] + bv[j] + (float)rv[j]);
                    *(half4_t*)(orow + o0) = hv;
                }
            }
        }
        __syncthreads();
        _Float16* gout = trunk + (size_t)bn * HT + (size_t)tw * H_;
        const _Float16* srow = Xs + (size_t)(4 + tw) * 68;
#pragma unroll
        for (int k2 = 0; k2 < 8; ++k2) {
            int u = k2 * 64 + ln;
            int r = u >> 3, c = u & 7;
            half8_t v = ld_b8(srow + r * 68 + c * 8);
            *(half8_t*)(gout + (size_t)r * H_ + c * 8) = v;
        }
    } else {
        float sv[2][16];
#pragma unroll
        for (int mt = 0; mt < 2; ++mt) {
#pragma unroll
            for (int rg = 0; rg < 4; ++rg) {
                int o0 = mt * 32 + rg * 8 + kg * 4;
                f32x4 bv = *(const f32x4*)(b2 + l * H_ + o0);
                half4_t r0 = *(const half4_t*)(Rs + (size_t)(tw + ln31) * 68 + o0);
                half4_t r1 = *(const half4_t*)(Rs + (size_t)(tw + 32 + ln31) * 68 + o0);
#pragma unroll
                for (int j = 0; j < 4; ++j) {
                    int r = rg * 4 + j;
                    float s = (acc[mt][0][r] + bv[j] + (float)r0[j])
                            + (acc[mt][1][r] + bv[j] + (float)r1[j]);
#pragma unroll
                    for (int off = 1; off < 32; off <<= 1) s += __shfl_xor(s, off);
                    sv[mt][r] = s;
                }
            }
        }
        __syncthreads();   // Xs reads done; reuse as reduction scratch
        float* red = (float*)Xs;
        if (ln31 == 0) {
#pragma unroll
            for (int mt = 0; mt < 2; ++mt)
#pragma unroll
                for (int r = 0; r < 16; ++r) {
                    int o = mt * 32 + (r & 3) + 8 * (r >> 2) + 4 * kg;
                    red[w * 64 + o] = sv[mt][r];
                }
        }
        __syncthreads();
        if (tid < 64) {
            float s = red[tid] + red[64 + tid] + red[128 + tid] + red[192 + tid];
            int b = bn / N, n = bn % N;
            atomicAdd(&feat[(size_t)b * FEAT_DIM + fbase + n * H_ + tid], s * (1.f / 256.f));
        }
    }
}

// adjmix: out = relu(adj @ sup + gb), LDS-transposed b128 output
template <int N, int MT, int KS>
__device__ void adjmix_impl(const _Float16* __restrict__ sup,
                            const half8_t* __restrict__ adjP,
                            const float* __restrict__ gb,
                            _Float16* __restrict__ out,
                            int blk, int l, _Float16* Ls, int tid) {
    constexpr int KP = KS * 16;
    constexpr int PITCH = KP + 4;
    int b = blk >> 7, cb = blk & 127;
    int colbase = cb * 128;

    for (int u = tid; u < KP * 16; u += 256) {
        int n = u >> 4, cs = u & 15;
        half8_t v;
        if (n < N) v = *(const half8_t*)(sup + (size_t)(b * N + n) * HT + colbase + cs * 8);
        else {
#pragma unroll
            for (int j = 0; j < 8; ++j) v[j] = (_Float16)0.f;
        }
#pragma unroll
        for (int j = 0; j < 8; ++j) Ls[(cs * 8 + j) * PITCH + n] = v[j];
    }
    __syncthreads();

    int ln = tid & 63;
    int w = __builtin_amdgcn_readfirstlane(tid >> 6);
    int ln31 = ln & 31, kg = ln >> 5;
    int colL = w * 32 + ln31;

    f32x16 acc[MT];
#pragma unroll
    for (int mt = 0; mt < MT; ++mt)
#pragma unroll
        for (int r = 0; r < 16; ++r) acc[mt][r] = 0.f;

#pragma unroll
    for (int ks = 0; ks < KS; ++ks) {
        half8_t bf = ld_b8(&Ls[colL * PITCH + ks * 16 + kg * 8]);
#pragma unroll
        for (int mt = 0; mt < MT; ++mt) {
            half8_t af = adjP[(size_t)(mt * 32 + ln31) * (KP / 8) + ks * 2 + kg];
            acc[mt] = __builtin_amdgcn_mfma_f32_32x32x16_f16(af, bf, acc[mt], 0, 0, 0);
        }
    }
    __syncthreads();   // staging reads done; reuse Ls as [m][132] out-transpose buffer

    float gbv = gb[l * H_ + (colL & 63)];   // [t][o] layout: o = col & 63
#pragma unroll
    for (int mt = 0; mt < MT; ++mt) {
#pragma unroll
        for (int r = 0; r < 16; ++r) {
            int m = mt * 32 + (r & 3) + 8 * (r >> 2) + 4 * kg;
            Ls[m * 132 + colL] = (_Float16)fmaxf(acc[mt][r] + gbv, 0.f);
        }
    }
    __syncthreads();

    for (int u = tid; u < N * 16; u += 256) {
        int m = u >> 4, c = u & 15;
        half8_t v = ld_b8(&Ls[m * 132 + c * 8]);
        *(half8_t*)(out + (size_t)(b * N + m) * HT + colbase + c * 8) = v;
    }
}

// fusion layer 1 (5504 -> 256), split-K, all 8 batches per unit
__device__ void fus1_unit(const Args& A, int blk, float* fv, int tid) {
    int ic = blk >> 1, kh = blk & 1;
    int base = ic * 128 + kh * 64;
    for (int u = tid; u < 8 * 64; u += 256) {
        int b = u >> 6, j = u & 63;
        fv[b * 64 + j] = A.feat[(size_t)b * FEAT_DIM + base + j];
    }
    __syncthreads();
    float acc[8];
#pragma unroll
    for (int b = 0; b < 8; ++b) acc[b] = 0.f;
    const float* wb = A.fus1_w + (size_t)base * 256 + tid;
    for (int i = 0; i < 64; ++i) {
        float wv = wb[(size_t)i * 256];
#pragma unroll
        for (int b = 0; b < 8; ++b) acc[b] = fmaf(fv[b * 64 + i], wv, acc[b]);
    }
#pragma unroll
    for (int b = 0; b < 8; ++b) atomicAdd(&A.p1[b * 256 + tid], acc[b]);
}

// fusion tail
__device__ void fus_tail_unit(const Args& A, int b, float* sbuf, int tid) {
    float* s1 = sbuf;
    float* s2 = sbuf + 256;
    float* s3 = sbuf + 384;
    s1[tid] = fmaxf(A.p1[b * 256 + tid] + A.fus1_b[tid], 0.f);
    __syncthreads();
    if (tid < 128) {
        float acc = A.fus2_b[tid];
        for (int i = 0; i < 256; ++i) acc = fmaf(s1[i], A.fus2_w[i * 128 + tid], acc);
        s2[tid] = fmaxf(acc, 0.f);
    }
    __syncthreads();
    if (tid < 64) {
        float acc = A.fus3_b[tid];
        for (int i = 0; i < 128; ++i) acc = fmaf(s2[i], A.fus3_w[i * 64 + tid], acc);
        s3[tid] = fmaxf(acc, 0.f);
    }
    __syncthreads();
    if (tid < 5) {
        float acc = A.fus4_b[tid];
        for (int i = 0; i < 64; ++i) acc = fmaf(s3[i], A.fus4_w[i * 5 + tid], acc);
        A.out[b * 5 + tid] = acc;
    }
}

// ---------------- the single cooperative kernel ----------------
__global__ __launch_bounds__(256, 2) void mega(Args A) {
    __shared__ __align__(16) _Float16 Xs[264 * 68];
    __shared__ __align__(16) _Float16 Rs[256 * 68];
    cg::grid_group grid = cg::this_grid();
    const int tid = threadIdx.x;
    const int GB = gridDim.x;
    const int nB = B_ * NB_;   // 136

    // phase 0: prep (2038) + proj (680) + head (8) — independent work
    for (int u = blockIdx.x; u < 2726; u += GB) {
        if (u < 2038) prep_unit(A, u, tid);
        else if (u < 2718) proj_unit(A, u - 2038, tid);
        else head_unit(A, u - 2718, tid);
    }
    __threadfence(); grid.sync(); __threadfence();

    for (int l = 0; l < L_; ++l) {
        for (int u = blockIdx.x; u < 680; u += GB) {
            __syncthreads();
            if (u < nB)
                convmix_unit(A.TrB, (const half8_t*)A.W3, A.B2,
                             (const half8_t*)A.GW3, A.SupB, u, l, Xs, tid);
            else
                convmix_unit(A.TrF, (const half8_t*)(A.W3 + 221184), A.B2 + 384,
                             (const half8_t*)(A.GW3 + 12288), A.SupF, u - nB, l, Xs, tid);
        }
        __threadfence(); grid.sync(); __threadfence();

        for (int u = blockIdx.x; u < 2048; u += GB) {
            __syncthreads();
            if (u < 1024)
                adjmix_impl<NB_, 1, 2>(A.SupB, (const half8_t*)A.adjPB, A.b_gcb, A.Gb,
                                       u, l, Xs, tid);
            else
                adjmix_impl<NF_, 3, 5>(A.SupF, (const half8_t*)A.adjPF, A.f_gcb, A.Gf,
                                       u - 1024, l, Xs, tid);
        }
        __threadfence(); grid.sync(); __threadfence();

        if (l < L_ - 1) {
            for (int u = blockIdx.x; u < 680; u += GB) {
                __syncthreads();
                if (u < nB)
                    conv2_unit<false>(A.Gb, (const half8_t*)(A.W3 + 110592), A.B2 + 192,
                                      A.TrB, NB_, 0, u, l, A.feat, Xs, Rs, tid);
                else
                    conv2_unit<false>(A.Gf, (const half8_t*)(A.W3 + 331776), A.B2 + 576,
                                      A.TrF, NF_, NB_ * H_, u - nB, l, A.feat, Xs, Rs, tid);
            }
        } else {
            for (int u = blockIdx.x; u < 680; u += GB) {
                __syncthreads();
                if (u < nB)
                    conv2_unit<true>(A.Gb, (const half8_t*)(A.W3 + 110592), A.B2 + 192,
                                     A.TrB, NB_, 0, u, l, A.feat, Xs, Rs, tid);
                else
                    conv2_unit<true>(A.Gf, (const half8_t*)(A.W3 + 331776), A.B2 + 576,
                                     A.TrF, NF_, NB_ * H_, u - nB, l, A.feat, Xs, Rs, tid);
            }
        }
        __threadfence(); grid.sync(); __threadfence();
    }

    for (int u = blockIdx.x; u < 86; u += GB) {
        __syncthreads();
        fus1_unit(A, u, (float*)Rs, tid);
    }
    __threadfence(); grid.sync(); __threadfence();

    for (int u = blockIdx.x; u < 8; u += GB) {
        __syncthreads();
        fus_tail_unit(A, u, (float*)Xs, tid);
    }
}

// ---------------- fallback multi-kernel path (identical math) ----------------
__global__ __launch_bounds__(256) void prep_all_k(Args A) {
    prep_unit(A, blockIdx.x, threadIdx.x);
}
__global__ __launch_bounds__(256) void proj_k(Args A) {
    int u = blockIdx.x;
    if (u < 680) proj_unit(A, u, threadIdx.x);
    else head_unit(A, u - 680, threadIdx.x);
}
__global__ __launch_bounds__(256, 2) void convmix_k(Args A, int l) {
    __shared__ __align__(16) _Float16 Xs[264 * 68];
    int u = blockIdx.x;
    if (u < 136)
        convmix_unit(A.TrB, (const half8_t*)A.W3, A.B2,
                     (const half8_t*)A.GW3, A.SupB, u, l, Xs, threadIdx.x);
    else
        convmix_unit(A.TrF, (const half8_t*)(A.W3 + 221184), A.B2 + 384,
                     (const half8_t*)(A.GW3 + 12288), A.SupF, u - 136, l, Xs, threadIdx.x);
}
__global__ __launch_bounds__(256) void adjmix_k(Args A, int l) {
    __shared__ __align__(16) _Float16 Ls[12800];
    int u = blockIdx.x;
    if (u < 1024)
        adjmix_impl<NB_, 1, 2>(A.SupB, (const half8_t*)A.adjPB, A.b_gcb, A.Gb, u, l, Ls, threadIdx.x);
    else
        adjmix_impl<NF_, 3, 5>(A.SupF, (const half8_t*)A.adjPF, A.f_gcb, A.Gf, u - 1024, l, Ls, threadIdx.x);
}
template <bool LAST>
__global__ __launch_bounds__(256, 2) void conv2_k(Args A, int l) {
    __shared__ __align__(16) _Float16 Xs[264 * 68];
    __shared__ __align__(16) _Float16 Rs[256 * 68];
    int u = blockIdx.x;
    if (u < 136)
        conv2_unit<LAST>(A.Gb, (const half8_t*)(A.W3 + 110592), A.B2 + 192,
                         A.TrB, NB_, 0, u, l, A.feat, Xs, Rs, threadIdx.x);
    else
        conv2_unit<LAST>(A.Gf, (const half8_t*)(A.W3 + 331776), A.B2 + 576,
                         A.TrF, NF_, NB_ * H_, u - 136, l, A.feat, Xs, Rs, threadIdx.x);
}
__global__ __launch_bounds__(256) void fus1_k(Args A) {
    __shared__ float fv[512];
    fus1_unit(A, blockIdx.x, fv, threadIdx.x);
}
__global__ __launch_bounds__(256) void fus_tail_k(Args A) {
    __shared__ float sb[448];
    fus_tail_unit(A, blockIdx.x, sb, threadIdx.x);
}

// ---------------- launch ----------------
extern "C" void kernel_launch(void* const* d_in, const int* in_sizes, int n_in,
                              void* d_out, int out_size, void* d_ws, size_t ws_size,
                              hipStream_t stream) {
    float* ws = (float*)d_ws;

    Args A;
    A.body_kps = (const float*)d_in[0];
    A.face_kps = (const float*)d_in[1];
    A.head_pose = (const float*)d_in[2];
    A.body_adj = (const float*)d_in[3];
    A.face_adj = (const float*)d_in[4];
    A.body_pw = (const float*)d_in[5];
    A.body_pb = (const float*)d_in[6];
    A.face_pw = (const float*)d_in[7];
    A.face_pb = (const float*)d_in[8];
    A.head_w = (const float*)d_in[9];
    A.head_b = (const float*)d_in[10];
    A.sb1 = ConvPrepSet{(const float*)d_in[11], (const float*)d_in[12], (const float*)d_in[13],
                        (const float*)d_in[14], (const float*)d_in[15], (const float*)d_in[16]};
    A.b_gcw = (const float*)d_in[17];
    A.b_gcb = (const float*)d_in[18];
    A.sb2 = ConvPrepSet{(const float*)d_in[19], (const float*)d_in[20], (const float*)d_in[21],
                        (const float*)d_in[22], (const float*)d_in[23], (const float*)d_in[24]};
    A.sf1 = ConvPrepSet{(const float*)d_in[25], (const float*)d_in[26], (const float*)d_in[27],
                        (const float*)d_in[28], (const float*)d_in[29], (const float*)d_in[30]};
    A.f_gcw = (const float*)d_in[31];
    A.f_gcb = (const float*)d_in[32];
    A.sf2 = ConvPrepSet{(const float*)d_in[33], (const float*)d_in[34], (const float*)d_in[35],
                        (const float*)d_in[36], (const float*)d_in[37], (const float*)d_in[38]};
    A.fus1_w = (const float*)d_in[39]; A.fus1_b = (const float*)d_in[40];
    A.fus2_w = (const float*)d_in[41]; A.fus2_b = (const float*)d_in[42];
    A.fus3_w = (const float*)d_in[43]; A.fus3_b = (const float*)d_in[44];
    A.fus4_w = (const float*)d_in[45]; A.fus4_b = (const float*)d_in[46];

    A.TrB  = (_Float16*)(ws + OFF_TB);
    A.TrF  = (_Float16*)(ws + OFF_TF);
    A.SupB = (_Float16*)(ws + OFF_SUPB);
    A.SupF = (_Float16*)(ws + OFF_SUPF);
    A.Gb   = (_Float16*)(ws + OFF_GB);
    A.Gf   = (_Float16*)(ws + OFF_GF);
    A.W3   = (_Float16*)(ws + OFF_W3);
    A.GW3  = (_Float16*)(ws + OFF_GW3);
    A.adjPB= (_Float16*)(ws + OFF_ADJPB);
    A.adjPF= (_Float16*)(ws + OFF_ADJPF);
    A.B2   = ws + OFF_B2;
    A.feat = ws + OFF_FEAT;
    A.p1   = ws + OFF_P1;
    A.out  = (float*)d_out;

    // one cooperative kernel for the whole network
    void* kargs[] = { (void*)&A };
    hipError_t st = hipLaunchCooperativeKernel(mega, dim3(512), dim3(256), kargs, 0u, stream);
    if (st != hipSuccess) {
        (void)hipGetLastError();
        st = hipLaunchCooperativeKernel(mega, dim3(256), dim3(256), kargs, 0u, stream);
    }
    if (st != hipSuccess) {
        (void)hipGetLastError();
        // fallback: multi-kernel path (identical math)
        prep_all_k<<<2038, 256, 0, stream>>>(A);
        proj_k<<<688, 256, 0, stream>>>(A);
        for (int l = 0; l < L_; ++l) {
            convmix_k<<<680, 256, 0, stream>>>(A, l);
            adjmix_k<<<2048, 256, 0, stream>>>(A, l);
            if (l < L_ - 1) conv2_k<false><<<680, 256, 0, stream>>>(A, l);
            else            conv2_k<true><<<680, 256, 0, stream>>>(A, l);
        }
        fus1_k<<<86, 256, 0, stream>>>(A);
        fus_tail_k<<<8, 256, 0, stream>>>(A);
    }
}

// Round 4
// 458.797 us; speedup vs baseline: 4.6099x; 4.6099x over previous
//
#include <hip/hip_runtime.h>

// ---------------- problem constants ----------------
constexpr int B_ = 8, T_ = 256, H_ = 64, L_ = 3, NB_ = 17, NF_ = 68, HP_ = 6, K_ = 9;
constexpr int FEAT_DIM = NB_ * H_ + NF_ * H_ + H_;   // 5504
constexpr int HT = H_ * T_;                          // 16384 per (b,n)

typedef _Float16 half4_t __attribute__((ext_vector_type(4)));
typedef _Float16 half8_t __attribute__((ext_vector_type(8)));
typedef float f32x16 __attribute__((ext_vector_type(16)));
typedef float f32x4 __attribute__((ext_vector_type(4)));

// ---------------- workspace layout (float units); activations f16 [bn][t][o] ----------------
constexpr size_t SZ_AB = (size_t)B_ * NB_ * HT;
constexpr size_t SZ_AF = (size_t)B_ * NF_ * HT;
constexpr size_t OFF_TB   = 0;
constexpr size_t OFF_TF   = OFF_TB + SZ_AB / 2;
constexpr size_t OFF_SUPB = OFF_TF + SZ_AF / 2;
constexpr size_t OFF_SUPF = OFF_SUPB + SZ_AB / 2;
constexpr size_t OFF_GB   = OFF_SUPF + SZ_AF / 2;
constexpr size_t OFF_GF   = OFF_GB + SZ_AB / 2;
constexpr size_t OFF_W3   = OFF_GF + SZ_AF / 2;      // 4 conv sets x 110592 f16
constexpr size_t OFF_GW3  = OFF_W3 + 4 * 55296;      // 2 x 12288 f16
constexpr size_t OFF_B2   = OFF_GW3 + 2 * 6144;      // 4 x 192 f32
constexpr size_t OFF_ADJPB= OFF_B2 + 768;            // 32x32 f16
constexpr size_t OFF_ADJPF= OFF_ADJPB + 512;         // 96x80 f16
constexpr size_t OFF_FEAT = OFF_ADJPF + 3840;        // 8x5504 f32
constexpr size_t OFF_P1   = OFF_FEAT + (size_t)B_ * FEAT_DIM;

struct ConvPrepSet { const float *w, *tb, *g, *bb, *m, *v; };

// ---------------- all pointers in one arg struct ----------------
struct Args {
    const float *body_kps, *face_kps, *head_pose, *body_adj, *face_adj;
    const float *body_pw, *body_pb, *face_pw, *face_pb, *head_w, *head_b;
    ConvPrepSet sb1, sb2, sf1, sf2;
    const float *b_gcw, *f_gcw, *b_gcb, *f_gcb;
    const float *fus1_w, *fus1_b, *fus2_w, *fus2_b, *fus3_w, *fus3_b, *fus4_w, *fus4_b;
    _Float16 *TrB, *TrF, *SupB, *SupF, *Gb, *Gf;
    _Float16 *W3, *GW3, *adjPB, *adjPF;
    float *B2, *p1, *feat;
    float *out;
};

// ---------------- small helpers ----------------
__device__ __forceinline__ half8_t ld_b8(const _Float16* p) {
    half4_t lo = *(const half4_t*)p;
    half4_t hi = *(const half4_t*)(p + 4);
    return __builtin_shufflevector(lo, hi, 0, 1, 2, 3, 4, 5, 6, 7);
}

__device__ __forceinline__ void st_b8(_Float16* p, half8_t v) {
    half4_t lo, hi;
#pragma unroll
    for (int j = 0; j < 4; ++j) { lo[j] = v[j]; hi[j] = v[4 + j]; }
    *(half4_t*)p = lo;
    *(half4_t*)(p + 4) = hi;
}

// stage f16 [t][o] (contiguous 128B rows) -> Xs[t+4][c], pitch 68; rows 0..263 = t -4..259
__device__ __forceinline__ void stage_full(const _Float16* __restrict__ xb,
                                           _Float16* __restrict__ Xs, int tid) {
    for (int u = tid; u < 264 * 8; u += 256) {
        int row = u >> 3, c = u & 7;
        int t = row - 4;
        half8_t v;
        if (t >= 0 && t < T_) {
            v = *(const half8_t*)(xb + (size_t)t * H_ + c * 8);
        } else {
#pragma unroll
            for (int j = 0; j < 8; ++j) v[j] = (_Float16)0.f;
        }
        st_b8(&Xs[row * 68 + c * 8], v);
    }
}

// stage residual trunk rows [t][o] -> Rs[t][c], pitch 68 (t = 0..255)
__device__ __forceinline__ void stage_res(const _Float16* __restrict__ xb,
                                          _Float16* __restrict__ Rs, int tid) {
    for (int u = tid; u < 256 * 8; u += 256) {
        int row = u >> 3, c = u & 7;
        half8_t v = *(const half8_t*)(xb + (size_t)row * H_ + c * 8);
        st_b8(&Rs[row * 68 + c * 8], v);
    }
}

// shared conv K-loop: 9 taps x 4 ks -> acc[o-tile][t-frag]
__device__ __forceinline__ void conv_kloop(const half8_t* __restrict__ wl,
                                           const _Float16* __restrict__ Xs,
                                           int tw, int ln31, int kg,
                                           f32x16 (&acc)[2][2]) {
    const _Float16* xr0 = Xs + (size_t)(tw + ln31) * 68;
#pragma unroll
    for (int tap = 0; tap < K_; ++tap) {
#pragma unroll
        for (int ks = 0; ks < 4; ++ks) {
            int i8 = ks * 2 + kg;
            half8_t a0 = wl[(tap * 8 + i8) * H_ + ln31];
            half8_t a1 = wl[(tap * 8 + i8) * H_ + 32 + ln31];
            half8_t b0 = ld_b8(xr0 + tap * 68 + i8 * 8);
            half8_t b1v = ld_b8(xr0 + (32 + tap) * 68 + i8 * 8);
            acc[0][0] = __builtin_amdgcn_mfma_f32_32x32x16_f16(a0, b0, acc[0][0], 0, 0, 0);
            acc[0][1] = __builtin_amdgcn_mfma_f32_32x32x16_f16(a0, b1v, acc[0][1], 0, 0, 0);
            acc[1][0] = __builtin_amdgcn_mfma_f32_32x32x16_f16(a1, b0, acc[1][0], 0, 0, 0);
            acc[1][1] = __builtin_amdgcn_mfma_f32_32x32x16_f16(a1, b1v, acc[1][1], 0, 0, 0);
        }
    }
}

// ---------------- convmix core: Xs pre-staged trunk -> sup (conv1+bn+relu, channel mix) ----------------
__device__ void convmix_core(const half8_t* __restrict__ wl,   // w1 + layer offset
                             const float* __restrict__ b1l,    // b1 + l*H_
                             const half8_t* __restrict__ gl,   // gc + layer offset
                             _Float16* __restrict__ supb,      // sup + bn*HT
                             _Float16* __restrict__ Xs, int tid) {
    int ln = tid & 63;
    int w = __builtin_amdgcn_readfirstlane(tid >> 6);
    int ln31 = ln & 31, kg = ln >> 5;
    int tw = w * 64;

    f32x16 acc[2][2];
#pragma unroll
    for (int mt = 0; mt < 2; ++mt)
#pragma unroll
        for (int f = 0; f < 2; ++f)
#pragma unroll
            for (int r = 0; r < 16; ++r) acc[mt][f][r] = 0.f;

    conv_kloop(wl, Xs, tw, ln31, kg, acc);
    __syncthreads();

    // conv1 epilogue: bias+relu -> mid row Xs[4+t][o]
#pragma unroll
    for (int f = 0; f < 2; ++f) {
        _Float16* mrow = Xs + (size_t)(4 + tw + f * 32 + ln31) * 68;
#pragma unroll
        for (int mt = 0; mt < 2; ++mt) {
#pragma unroll
            for (int rg = 0; rg < 4; ++rg) {
                int o0 = mt * 32 + rg * 8 + kg * 4;
                f32x4 bv = *(const f32x4*)(b1l + o0);
                half4_t hv;
#pragma unroll
                for (int j = 0; j < 4; ++j)
                    hv[j] = (_Float16)fmaxf(acc[mt][f][rg * 4 + j] + bv[j], 0.f);
                *(half4_t*)(mrow + o0) = hv;
            }
        }
    }
    __syncthreads();

    // channel mix (K=64)
    f32x16 acc2[2][2];
#pragma unroll
    for (int mt = 0; mt < 2; ++mt)
#pragma unroll
        for (int f = 0; f < 2; ++f)
#pragma unroll
            for (int r = 0; r < 16; ++r) acc2[mt][f][r] = 0.f;
    const _Float16* mrow0 = Xs + (size_t)(4 + tw + ln31) * 68;
#pragma unroll
    for (int ks = 0; ks < 4; ++ks) {
        int i8 = ks * 2 + kg;
        half8_t a0 = gl[i8 * H_ + ln31];
        half8_t a1 = gl[i8 * H_ + 32 + ln31];
        half8_t b0 = ld_b8(mrow0 + i8 * 8);
        half8_t b1v = ld_b8(mrow0 + 32 * 68 + i8 * 8);
        acc2[0][0] = __builtin_amdgcn_mfma_f32_32x32x16_f16(a0, b0, acc2[0][0], 0, 0, 0);
        acc2[0][1] = __builtin_amdgcn_mfma_f32_32x32x16_f16(a0, b1v, acc2[0][1], 0, 0, 0);
        acc2[1][0] = __builtin_amdgcn_mfma_f32_32x32x16_f16(a1, b0, acc2[1][0], 0, 0, 0);
        acc2[1][1] = __builtin_amdgcn_mfma_f32_32x32x16_f16(a1, b1v, acc2[1][1], 0, 0, 0);
    }

    // write acc2 -> Xs[4+t][o] (wave-own rows), then coalesced b128 copy-out
#pragma unroll
    for (int f = 0; f < 2; ++f) {
        _Float16* orow = Xs + (size_t)(4 + tw + f * 32 + ln31) * 68;
#pragma unroll
        for (int mt = 0; mt < 2; ++mt) {
#pragma unroll
            for (int rg = 0; rg < 4; ++rg) {
                int o0 = mt * 32 + rg * 8 + kg * 4;
                half4_t hv;
#pragma unroll
                for (int j = 0; j < 4; ++j)
                    hv[j] = (_Float16)acc2[mt][f][rg * 4 + j];
                *(half4_t*)(orow + o0) = hv;
            }
        }
    }
    __syncthreads();
    _Float16* gout = supb + (size_t)tw * H_;
    const _Float16* srow = Xs + (size_t)(4 + tw) * 68;
#pragma unroll
    for (int k2 = 0; k2 < 8; ++k2) {
        int u = k2 * 64 + ln;
        int r = u >> 3, c = u & 7;
        half8_t v = ld_b8(srow + r * 68 + c * 8);
        *(half8_t*)(gout + (size_t)r * H_ + c * 8) = v;
    }
}

// ---------------- prep: fold BN into conv W; gcw pack; adj pad; zero p1/feat ----------------
__global__ __launch_bounds__(256) void prep_k(Args A) {
    int blk = blockIdx.x;
    int tid = threadIdx.x;
    if (blk < 1728) {                       // conv-weight fold: 4 sets x 432 blocks
        int set = blk / 432;
        int bx = blk % 432;
        ConvPrepSet s = (set == 0) ? A.sb1 : (set == 1) ? A.sb2 : (set == 2) ? A.sf1 : A.sf2;
        int idx = bx * 256 + tid;           // < 110592
        int k = idx % K_; int r = idx / K_;
        int i = r % H_; r /= H_;
        int o = r % H_; int l = r / H_;
        float sc = s.g[l * H_ + o] * rsqrtf(s.v[l * H_ + o] + 1e-5f);
        A.W3[(size_t)set * 110592 + ((((l * K_ + k) * 8 + (i >> 3)) * H_ + o) * 8) + (i & 7)]
            = (_Float16)(s.w[idx] * sc);
        if (i == 0 && k == 0)
            A.B2[set * 192 + l * H_ + o] =
                s.tb[l * H_ + o] * sc + s.bb[l * H_ + o] - s.m[l * H_ + o] * sc;
    } else if (blk < 1824) {                // gc-weight pack: 2 sets x 48 blocks
        int set = (blk - 1728) / 48;
        int bx = (blk - 1728) % 48;
        const float* gw = set ? A.f_gcw : A.b_gcw;
        int idx = bx * 256 + tid;           // < 12288
        int o = idx % H_; int r = idx / H_;
        int c = r % H_; int l = r / H_;
        A.GW3[(size_t)set * 12288 + (((l * 8 + (c >> 3)) * H_ + o) * 8) + (c & 7)]
            = (_Float16)gw[idx];
    } else {                                // misc: adj pad + zero p1/feat
        int idx = (blk - 1824) * 256 + tid;
        if (idx < 1024) {
            int m = idx >> 5, k = idx & 31;
            A.adjPB[idx] = (m < NB_ && k < NB_) ? (_Float16)A.body_adj[m * NB_ + k] : (_Float16)0.f;
        } else if (idx < 8704) {
            int j = idx - 1024;
            int m = j / 80, k = j % 80;
            A.adjPF[j] = (m < NF_ && k < NF_) ? (_Float16)A.face_adj[m * NF_ + k] : (_Float16)0.f;
        } else if (idx < 10752) {
            A.p1[idx - 8704] = 0.f;
        } else if (idx < 10752 + B_ * FEAT_DIM) {
            A.feat[idx - 10752] = 0.f;
        }
    }
}

// ---------------- fused proj + convmix(l=0): one block per bn ----------------
__global__ __launch_bounds__(256, 2) void projcm_k(Args A) {
    __shared__ __align__(16) _Float16 Xs[264 * 68];
    int blk = blockIdx.x, tid = threadIdx.x;
    bool isB = blk < B_ * NB_;
    int bn = isB ? blk : blk - B_ * NB_;
    const float* kps = isB ? A.body_kps : A.face_kps;
    const float* pw  = isB ? A.body_pw  : A.face_pw;
    const float* pb  = isB ? A.body_pb  : A.face_pb;
    _Float16* trunk  = isB ? A.TrB : A.TrF;
    int N = isB ? NB_ : NF_;
    int b = bn / N, n = bn % N;

    // proj: thread t computes 64 channels -> Xs row (4+t) AND global trunk
    {
        int t = tid;
        float x0 = kps[((size_t)b * T_ + t) * (N * 2) + n * 2 + 0];
        float x1 = kps[((size_t)b * T_ + t) * (N * 2) + n * 2 + 1];
        _Float16* ob = trunk + (size_t)bn * HT + (size_t)t * H_;
        _Float16* xr = Xs + (size_t)(4 + t) * 68;
#pragma unroll
        for (int cg2 = 0; cg2 < 8; ++cg2) {
            half8_t v;
#pragma unroll
            for (int j = 0; j < 8; ++j) {
                int c = cg2 * 8 + j;
                v[j] = (_Float16)fmaf(x0, pw[c], fmaf(x1, pw[H_ + c], pb[c]));
            }
            *(half8_t*)(ob + cg2 * 8) = v;
            st_b8(xr + cg2 * 8, v);
        }
        if (tid < 64) {     // zero the 8 halo rows (t = -4..-1, 256..259)
            int r4 = tid >> 3, c = tid & 7;
            int row = (r4 < 4) ? r4 : 256 + r4;
            half8_t z;
#pragma unroll
            for (int j = 0; j < 8; ++j) z[j] = (_Float16)0.f;
            st_b8(&Xs[row * 68 + c * 8], z);
        }
    }
    __syncthreads();

    const half8_t* w1 = (const half8_t*)(A.W3 + (isB ? 0 : 221184));     // l=0 slice
    const float* b1l  = isB ? A.B2 : A.B2 + 384;
    const half8_t* gl = (const half8_t*)(A.GW3 + (isB ? 0 : 12288));
    _Float16* supb = (isB ? A.SupB : A.SupF) + (size_t)bn * HT;
    convmix_core(w1, b1l, gl, supb, Xs, tid);
}

// ---------------- adjmix: out = relu(adj @ sup + gb), LDS-transposed b128 output ----------------
template <int N, int MT, int KS>
__device__ void adjmix_impl(const _Float16* __restrict__ sup,
                            const half8_t* __restrict__ adjP,
                            const float* __restrict__ gb,
                            _Float16* __restrict__ out,
                            int blk, int l, _Float16* Ls, int tid) {
    constexpr int KP = KS * 16;
    constexpr int PITCH = KP + 4;
    int b = blk >> 7, cb = blk & 127;
    int colbase = cb * 128;

    for (int u = tid; u < KP * 16; u += 256) {
        int n = u >> 4, cs = u & 15;
        half8_t v;
        if (n < N) v = *(const half8_t*)(sup + (size_t)(b * N + n) * HT + colbase + cs * 8);
        else {
#pragma unroll
            for (int j = 0; j < 8; ++j) v[j] = (_Float16)0.f;
        }
#pragma unroll
        for (int j = 0; j < 8; ++j) Ls[(cs * 8 + j) * PITCH + n] = v[j];
    }
    __syncthreads();

    int ln = tid & 63;
    int w = __builtin_amdgcn_readfirstlane(tid >> 6);
    int ln31 = ln & 31, kg = ln >> 5;
    int colL = w * 32 + ln31;

    f32x16 acc[MT];
#pragma unroll
    for (int mt = 0; mt < MT; ++mt)
#pragma unroll
        for (int r = 0; r < 16; ++r) acc[mt][r] = 0.f;

#pragma unroll
    for (int ks = 0; ks < KS; ++ks) {
        half8_t bf = ld_b8(&Ls[colL * PITCH + ks * 16 + kg * 8]);
#pragma unroll
        for (int mt = 0; mt < MT; ++mt) {
            half8_t af = adjP[(size_t)(mt * 32 + ln31) * (KP / 8) + ks * 2 + kg];
            acc[mt] = __builtin_amdgcn_mfma_f32_32x32x16_f16(af, bf, acc[mt], 0, 0, 0);
        }
    }
    __syncthreads();   // staging reads done; reuse Ls as [m][132] out-transpose buffer

    float gbv = gb[l * H_ + (colL & 63)];   // [t][o] layout: o = col & 63
#pragma unroll
    for (int mt = 0; mt < MT; ++mt) {
#pragma unroll
        for (int r = 0; r < 16; ++r) {
            int m = mt * 32 + (r & 3) + 8 * (r >> 2) + 4 * kg;
            Ls[m * 132 + colL] = (_Float16)fmaxf(acc[mt][r] + gbv, 0.f);
        }
    }
    __syncthreads();

    for (int u = tid; u < N * 16; u += 256) {
        int m = u >> 4, c = u & 15;
        half8_t v = ld_b8(&Ls[m * 132 + c * 8]);
        *(half8_t*)(out + (size_t)(b * N + m) * HT + colbase + c * 8) = v;
    }
}

__global__ __launch_bounds__(256) void adjmix_k(Args A, int l) {
    __shared__ __align__(16) _Float16 Ls[12800];
    int blk = blockIdx.x, tid = threadIdx.x;
    if (blk < 1024)
        adjmix_impl<NB_, 1, 2>(A.SupB, (const half8_t*)A.adjPB, A.b_gcb, A.Gb, blk, l, Ls, tid);
    else
        adjmix_impl<NF_, 3, 5>(A.SupF, (const half8_t*)A.adjPF, A.f_gcb, A.Gf, blk - 1024, l, Ls, tid);
}

// ---------------- fused conv2(l)(+bn+res) + convmix(l+1): one block per bn ----------------
__global__ __launch_bounds__(256, 2) void c2cm_k(Args A, int l) {
    __shared__ __align__(16) _Float16 Xs[264 * 68];
    __shared__ __align__(16) _Float16 Rs[256 * 68];
    int blk = blockIdx.x, tid = threadIdx.x;
    bool isB = blk < B_ * NB_;
    int bn = isB ? blk : blk - B_ * NB_;
    const _Float16* G = isB ? A.Gb : A.Gf;
    _Float16* trunk   = isB ? A.TrB : A.TrF;
    const half8_t* w2 = (const half8_t*)(A.W3 + (isB ? 110592 : 331776)) + (size_t)l * (K_ * 8 * H_);
    const float* b2l  = (isB ? A.B2 + 192 : A.B2 + 576) + l * H_;

    stage_full(G + (size_t)bn * HT, Xs, tid);
    stage_res(trunk + (size_t)bn * HT, Rs, tid);
    __syncthreads();

    int ln = tid & 63;
    int w = __builtin_amdgcn_readfirstlane(tid >> 6);
    int ln31 = ln & 31, kg = ln >> 5;
    int tw = w * 64;

    f32x16 acc[2][2];
#pragma unroll
    for (int mt = 0; mt < 2; ++mt)
#pragma unroll
        for (int f = 0; f < 2; ++f)
#pragma unroll
            for (int r = 0; r < 16; ++r) acc[mt][f][r] = 0.f;

    conv_kloop(w2, Xs, tw, ln31, kg, acc);
    __syncthreads();   // all conv B-reads done before overwriting Xs rows

    // epilogue: y = acc + b2 + res -> Xs[4+t][o] (f16, same rounding as before)
#pragma unroll
    for (int f = 0; f < 2; ++f) {
        int row = tw + f * 32 + ln31;
        _Float16* orow = Xs + (size_t)(4 + row) * 68;
        const _Float16* rrow = Rs + (size_t)row * 68;
#pragma unroll
        for (int mt = 0; mt < 2; ++mt) {
#pragma unroll
            for (int rg = 0; rg < 4; ++rg) {
                int o0 = mt * 32 + rg * 8 + kg * 4;
                f32x4 bv = *(const f32x4*)(b2l + o0);
                half4_t rv = *(const half4_t*)(rrow + o0);
                half4_t hv;
#pragma unroll
                for (int j = 0; j < 4; ++j)
                    hv[j] = (_Float16)(acc[mt][f][rg * 4 + j] + bv[j] + (float)rv[j]);
                *(half4_t*)(orow + o0) = hv;
            }
        }
    }
    __syncthreads();

    // copy new trunk out (wave-own rows), Xs now holds staged trunk for convmix(l+1)
    {
        _Float16* gout = trunk + (size_t)bn * HT + (size_t)tw * H_;
        const _Float16* srow = Xs + (size_t)(4 + tw) * 68;
#pragma unroll
        for (int k2 = 0; k2 < 8; ++k2) {
            int u = k2 * 64 + ln;
            int r = u >> 3, c = u & 7;
            half8_t v = ld_b8(srow + r * 68 + c * 8);
            *(half8_t*)(gout + (size_t)r * H_ + c * 8) = v;
        }
    }

    // convmix(l+1) straight from LDS (halo rows still zero from stage_full)
    const half8_t* w1 = (const half8_t*)(A.W3 + (isB ? 0 : 221184)) + (size_t)(l + 1) * (K_ * 8 * H_);
    const float* b1l  = (isB ? A.B2 : A.B2 + 384) + (l + 1) * H_;
    const half8_t* gl = (const half8_t*)(A.GW3 + (isB ? 0 : 12288)) + (size_t)(l + 1) * (8 * H_);
    _Float16* supb = (isB ? A.SupB : A.SupF) + (size_t)bn * HT;
    convmix_core(w1, b1l, gl, supb, Xs, tid);
}

// ---------------- conv2(2,LAST): mean-pool -> feat; extra blocks do head stream ----------------
__global__ __launch_bounds__(256, 2) void c2last_k(Args A) {
    __shared__ __align__(16) _Float16 Xs[264 * 68];
    __shared__ __align__(16) _Float16 Rs[256 * 68];
    int blk = blockIdx.x, tid = threadIdx.x;
    if (blk >= 680) {              // head stream: 8 blocks
        int b = blk - 680;
        if (tid < 64) {
            int c = tid;
            float w0 = A.head_w[c], w1 = A.head_w[64 + c], w2 = A.head_w[128 + c],
                  w3 = A.head_w[192 + c], w4 = A.head_w[256 + c], w5 = A.head_w[320 + c];
            float bias = A.head_b[c];
            float acc = 0.f;
            for (int t = 0; t < T_; ++t) {
                const float* xr = A.head_pose + ((size_t)b * T_ + t) * HP_;
                float s = fmaf(xr[0], w0, fmaf(xr[1], w1, fmaf(xr[2], w2,
                          fmaf(xr[3], w3, fmaf(xr[4], w4, fmaf(xr[5], w5, bias))))));
                acc += fmaxf(s, 0.f);
            }
            A.feat[(size_t)b * FEAT_DIM + NB_ * H_ + NF_ * H_ + c] = acc * (1.f / 256.f);
        }
        return;
    }
    constexpr int l = L_ - 1;
    bool isB = blk < B_ * NB_;
    int bn = isB ? blk : blk - B_ * NB_;
    const _Float16* G = isB ? A.Gb : A.Gf;
    _Float16* trunk   = isB ? A.TrB : A.TrF;
    const half8_t* w2 = (const half8_t*)(A.W3 + (isB ? 110592 : 331776)) + (size_t)l * (K_ * 8 * H_);
    const float* b2l  = (isB ? A.B2 + 192 : A.B2 + 576) + l * H_;
    int N = isB ? NB_ : NF_;
    int fbase = isB ? 0 : NB_ * H_;

    stage_full(G + (size_t)bn * HT, Xs, tid);
    stage_res(trunk + (size_t)bn * HT, Rs, tid);
    __syncthreads();

    int ln = tid & 63;
    int w = __builtin_amdgcn_readfirstlane(tid >> 6);
    int ln31 = ln & 31, kg = ln >> 5;
    int tw = w * 64;

    f32x16 acc[2][2];
#pragma unroll
    for (int mt = 0; mt < 2; ++mt)
#pragma unroll
        for (int f = 0; f < 2; ++f)
#pragma unroll
            for (int r = 0; r < 16; ++r) acc[mt][f][r] = 0.f;

    conv_kloop(w2, Xs, tw, ln31, kg, acc);

    // mean-pool over t: s = (acc0 + b2 + res0) + (acc1 + b2 + res1), reduce 32 lanes
    float sv[2][16];
#pragma unroll
    for (int mt = 0; mt < 2; ++mt) {
#pragma unroll
        for (int rg = 0; rg < 4; ++rg) {
            int o0 = mt * 32 + rg * 8 + kg * 4;
            f32x4 bv = *(const f32x4*)(b2l + o0);
            half4_t r0 = *(const half4_t*)(Rs + (size_t)(tw + ln31) * 68 + o0);
            half4_t r1 = *(const half4_t*)(Rs + (size_t)(tw + 32 + ln31) * 68 + o0);
#pragma unroll
            for (int j = 0; j < 4; ++j) {
                int r = rg * 4 + j;
                float s = (acc[mt][0][r] + bv[j] + (float)r0[j])
                        + (acc[mt][1][r] + bv[j] + (float)r1[j]);
#pragma unroll
                for (int off = 1; off < 32; off <<= 1) s += __shfl_xor(s, off);
                sv[mt][r] = s;
            }
        }
    }
    __syncthreads();   // Xs reads done; reuse as reduction scratch
    float* red = (float*)Xs;
    if (ln31 == 0) {
#pragma unroll
        for (int mt = 0; mt < 2; ++mt)
#pragma unroll
            for (int r = 0; r < 16; ++r) {
                int o = mt * 32 + (r & 3) + 8 * (r >> 2) + 4 * kg;
                red[w * 64 + o] = sv[mt][r];
            }
    }
    __syncthreads();
    if (tid < 64) {
        float s = red[tid] + red[64 + tid] + red[128 + tid] + red[192 + tid];
        int b = bn / N, n = bn % N;
        atomicAdd(&A.feat[(size_t)b * FEAT_DIM + fbase + n * H_ + tid], s * (1.f / 256.f));
    }
}

// ---------------- fusion layer 1 (5504 -> 256), split-K, all 8 batches per block ----------------
__global__ __launch_bounds__(256) void fus1_k(Args A) {
    __shared__ float fv[8][64];
    int blk = blockIdx.x;          // 86 = 43 ic * 2 khalf
    int ic = blk >> 1, kh = blk & 1;
    int base = ic * 128 + kh * 64;
    int tid = threadIdx.x;
    for (int u = tid; u < 8 * 64; u += 256) {
        int b = u >> 6, j = u & 63;
        fv[b][j] = A.feat[(size_t)b * FEAT_DIM + base + j];
    }
    __syncthreads();
    float acc[8];
#pragma unroll
    for (int b = 0; b < 8; ++b) acc[b] = 0.f;
    const float* wb = A.fus1_w + (size_t)base * 256 + tid;
    for (int i = 0; i < 64; ++i) {
        float wv = wb[(size_t)i * 256];
#pragma unroll
        for (int b = 0; b < 8; ++b) acc[b] = fmaf(fv[b][i], wv, acc[b]);
    }
#pragma unroll
    for (int b = 0; b < 8; ++b) atomicAdd(&A.p1[b * 256 + tid], acc[b]);
}

// ---------------- fusion tail ----------------
__global__ __launch_bounds__(256) void fus_tail_k(Args A) {
    __shared__ float s1[256], s2[128], s3[64];
    int b = blockIdx.x, tid = threadIdx.x;
    s1[tid] = fmaxf(A.p1[b * 256 + tid] + A.fus1_b[tid], 0.f);
    __syncthreads();
    if (tid < 128) {
        float acc = A.fus2_b[tid];
        for (int i = 0; i < 256; ++i) acc = fmaf(s1[i], A.fus2_w[i * 128 + tid], acc);
        s2[tid] = fmaxf(acc, 0.f);
    }
    __syncthreads();
    if (tid < 64) {
        float acc = A.fus3_b[tid];
        for (int i = 0; i < 128; ++i) acc = fmaf(s2[i], A.fus3_w[i * 64 + tid], acc);
        s3[tid] = fmaxf(acc, 0.f);
    }
    __syncthreads();
    if (tid < 5) {
        float acc = A.fus4_b[tid];
        for (int i = 0; i < 64; ++i) acc = fmaf(s3[i], A.fus4_w[i * 5 + tid], acc);
        A.out[b * 5 + tid] = acc;
    }
}

// ---------------- launch ----------------
extern "C" void kernel_launch(void* const* d_in, const int* in_sizes, int n_in,
                              void* d_out, int out_size, void* d_ws, size_t ws_size,
                              hipStream_t stream) {
    float* ws = (float*)d_ws;

    Args A;
    A.body_kps = (const float*)d_in[0];
    A.face_kps = (const float*)d_in[1];
    A.head_pose = (const float*)d_in[2];
    A.body_adj = (const float*)d_in[3];
    A.face_adj = (const float*)d_in[4];
    A.body_pw = (const float*)d_in[5];
    A.body_pb = (const float*)d_in[6];
    A.face_pw = (const float*)d_in[7];
    A.face_pb = (const float*)d_in[8];
    A.head_w = (const float*)d_in[9];
    A.head_b = (const float*)d_in[10];
    A.sb1 = ConvPrepSet{(const float*)d_in[11], (const float*)d_in[12], (const float*)d_in[13],
                        (const float*)d_in[14], (const float*)d_in[15], (const float*)d_in[16]};
    A.b_gcw = (const float*)d_in[17];
    A.b_gcb = (const float*)d_in[18];
    A.sb2 = ConvPrepSet{(const float*)d_in[19], (const float*)d_in[20], (const float*)d_in[21],
                        (const float*)d_in[22], (const float*)d_in[23], (const float*)d_in[24]};
    A.sf1 = ConvPrepSet{(const float*)d_in[25], (const float*)d_in[26], (const float*)d_in[27],
                        (const float*)d_in[28], (const float*)d_in[29], (const float*)d_in[30]};
    A.f_gcw = (const float*)d_in[31];
    A.f_gcb = (const float*)d_in[32];
    A.sf2 = ConvPrepSet{(const float*)d_in[33], (const float*)d_in[34], (const float*)d_in[35],
                        (const float*)d_in[36], (const float*)d_in[37], (const float*)d_in[38]};
    A.fus1_w = (const float*)d_in[39]; A.fus1_b = (const float*)d_in[40];
    A.fus2_w = (const float*)d_in[41]; A.fus2_b = (const float*)d_in[42];
    A.fus3_w = (const float*)d_in[43]; A.fus3_b = (const float*)d_in[44];
    A.fus4_w = (const float*)d_in[45]; A.fus4_b = (const float*)d_in[46];

    A.TrB  = (_Float16*)(ws + OFF_TB);
    A.TrF  = (_Float16*)(ws + OFF_TF);
    A.SupB = (_Float16*)(ws + OFF_SUPB);
    A.SupF = (_Float16*)(ws + OFF_SUPF);
    A.Gb   = (_Float16*)(ws + OFF_GB);
    A.Gf   = (_Float16*)(ws + OFF_GF);
    A.W3   = (_Float16*)(ws + OFF_W3);
    A.GW3  = (_Float16*)(ws + OFF_GW3);
    A.adjPB= (_Float16*)(ws + OFF_ADJPB);
    A.adjPF= (_Float16*)(ws + OFF_ADJPF);
    A.B2   = ws + OFF_B2;
    A.feat = ws + OFF_FEAT;
    A.p1   = ws + OFF_P1;
    A.out  = (float*)d_out;

    prep_k<<<2038, 256, 0, stream>>>(A);
    projcm_k<<<680, 256, 0, stream>>>(A);          // proj + convmix(0)
    for (int l = 0; l < L_; ++l) {
        adjmix_k<<<2048, 256, 0, stream>>>(A, l);
        if (l < L_ - 1)
            c2cm_k<<<680, 256, 0, stream>>>(A, l); // conv2(l) + convmix(l+1)
        else
            c2last_k<<<688, 256, 0, stream>>>(A);  // conv2(2)+pool + head
    }
    fus1_k<<<86, 256, 0, stream>>>(A);
    fus_tail_k<<<8, 256, 0, stream>>>(A);
}

// Round 5
// 382.864 us; speedup vs baseline: 5.5242x; 1.1983x over previous
//
#include <hip/hip_runtime.h>

// ---------------- problem constants ----------------
constexpr int B_ = 8, T_ = 256, H_ = 64, L_ = 3, NB_ = 17, NF_ = 68, HP_ = 6, K_ = 9;
constexpr int FEAT_DIM = NB_ * H_ + NF_ * H_ + H_;   // 5504
constexpr int HT = H_ * T_;                          // 16384 per (b,n)

typedef _Float16 half4_t __attribute__((ext_vector_type(4)));
typedef _Float16 half8_t __attribute__((ext_vector_type(8)));
typedef float f32x16 __attribute__((ext_vector_type(16)));
typedef float f32x4 __attribute__((ext_vector_type(4)));

// ---------------- workspace layout (float units); activations f16 [bn][t][o] ----------------
constexpr size_t SZ_AB = (size_t)B_ * NB_ * HT;
constexpr size_t SZ_AF = (size_t)B_ * NF_ * HT;
constexpr size_t OFF_TB   = 0;
constexpr size_t OFF_TF   = OFF_TB + SZ_AB / 2;
constexpr size_t OFF_SUPB = OFF_TF + SZ_AF / 2;
constexpr size_t OFF_SUPF = OFF_SUPB + SZ_AB / 2;
constexpr size_t OFF_GB   = OFF_SUPF + SZ_AF / 2;
constexpr size_t OFF_GF   = OFF_GB + SZ_AB / 2;
constexpr size_t OFF_W3   = OFF_GF + SZ_AF / 2;      // 4 conv sets x 110592 f16
constexpr size_t OFF_GW3  = OFF_W3 + 4 * 55296;      // 2 x 12288 f16
constexpr size_t OFF_B2   = OFF_GW3 + 2 * 6144;      // 4 x 192 f32
constexpr size_t OFF_ADJPB= OFF_B2 + 768;            // 32x32 f16
constexpr size_t OFF_ADJPF= OFF_ADJPB + 512;         // 96x80 f16
constexpr size_t OFF_FEAT = OFF_ADJPF + 3840;        // 8x5504 f32
constexpr size_t OFF_P1   = OFF_FEAT + (size_t)B_ * FEAT_DIM;

struct ConvPrepSet { const float *w, *tb, *g, *bb, *m, *v; };

// ---------------- all pointers in one arg struct ----------------
struct Args {
    const float *body_kps, *face_kps, *head_pose, *body_adj, *face_adj;
    const float *body_pw, *body_pb, *face_pw, *face_pb, *head_w, *head_b;
    ConvPrepSet sb1, sb2, sf1, sf2;
    const float *b_gcw, *f_gcw, *b_gcb, *f_gcb;
    const float *fus1_w, *fus1_b, *fus2_w, *fus2_b, *fus3_w, *fus3_b, *fus4_w, *fus4_b;
    _Float16 *TrB, *TrF, *SupB, *SupF, *Gb, *Gf;
    _Float16 *W3, *GW3, *adjPB, *adjPF;
    float *B2, *p1, *feat;
    float *out;
};

// ---------------- small helpers ----------------
__device__ __forceinline__ half8_t ld_b8(const _Float16* p) {
    half4_t lo = *(const half4_t*)p;
    half4_t hi = *(const half4_t*)(p + 4);
    return __builtin_shufflevector(lo, hi, 0, 1, 2, 3, 4, 5, 6, 7);
}

__device__ __forceinline__ void st_b8(_Float16* p, half8_t v) {
    half4_t lo, hi;
#pragma unroll
    for (int j = 0; j < 4; ++j) { lo[j] = v[j]; hi[j] = v[4 + j]; }
    *(half4_t*)p = lo;
    *(half4_t*)(p + 4) = hi;
}

// stage f16 [t][o] chunk -> Xs[136][68]; rows 0..135 = t (tc*128 - 4 .. tc*128 + 131), OOB=0
__device__ __forceinline__ void stage_chunk(const _Float16* __restrict__ xb,
                                            _Float16* __restrict__ Xs, int tc, int tid) {
    for (int u = tid; u < 136 * 8; u += 256) {
        int row = u >> 3, c = u & 7;
        int t = tc * 128 + row - 4;
        half8_t v;
        if (t >= 0 && t < T_) {
            v = *(const half8_t*)(xb + (size_t)t * H_ + c * 8);
        } else {
#pragma unroll
            for (int j = 0; j < 8; ++j) v[j] = (_Float16)0.f;
        }
        st_b8(&Xs[row * 68 + c * 8], v);
    }
}

// stage residual chunk rows [t][o] -> Rs[128][68] (t = tc*128 .. tc*128+127)
__device__ __forceinline__ void stage_res_chunk(const _Float16* __restrict__ xb,
                                                _Float16* __restrict__ Rs, int tc, int tid) {
    for (int u = tid; u < 128 * 8; u += 256) {
        int row = u >> 3, c = u & 7;
        half8_t v = *(const half8_t*)(xb + (size_t)(tc * 128 + row) * H_ + c * 8);
        st_b8(&Rs[row * 68 + c * 8], v);
    }
}

// chunked conv K-loop: 9 taps x 4 ks -> acc[o-tile], wave covers 32 t-cols
__device__ __forceinline__ void conv_kloop(const half8_t* __restrict__ wl,
                                           const _Float16* __restrict__ Xs,
                                           int trow, int ln31, int kg,
                                           f32x16 (&acc)[2]) {
    const _Float16* xr0 = Xs + (size_t)(trow + ln31) * 68;
#pragma unroll
    for (int tap = 0; tap < K_; ++tap) {
#pragma unroll
        for (int ks = 0; ks < 4; ++ks) {
            int i8 = ks * 2 + kg;
            half8_t a0 = wl[(tap * 8 + i8) * H_ + ln31];
            half8_t a1 = wl[(tap * 8 + i8) * H_ + 32 + ln31];
            half8_t bf = ld_b8(xr0 + tap * 68 + i8 * 8);
            acc[0] = __builtin_amdgcn_mfma_f32_32x32x16_f16(a0, bf, acc[0], 0, 0, 0);
            acc[1] = __builtin_amdgcn_mfma_f32_32x32x16_f16(a1, bf, acc[1], 0, 0, 0);
        }
    }
}

// ---------------- convmix core (chunked): Xs pre-staged -> sup chunk ----------------
__device__ void convmix_core(const half8_t* __restrict__ wl,   // w1 + layer offset
                             const float* __restrict__ b1l,    // b1 + l*H_
                             const half8_t* __restrict__ gl,   // gc + layer offset
                             _Float16* __restrict__ supb,      // sup + bn*HT
                             int tc, _Float16* __restrict__ Xs, int tid) {
    int ln = tid & 63;
    int w = __builtin_amdgcn_readfirstlane(tid >> 6);
    int ln31 = ln & 31, kg = ln >> 5;
    int trow = w * 32;

    f32x16 acc[2];
#pragma unroll
    for (int mt = 0; mt < 2; ++mt)
#pragma unroll
        for (int r = 0; r < 16; ++r) acc[mt][r] = 0.f;

    conv_kloop(wl, Xs, trow, ln31, kg, acc);
    __syncthreads();

    // conv1 epilogue: bias+relu -> mid row Xs[4+t][o]
    _Float16* mrow = Xs + (size_t)(4 + trow + ln31) * 68;
#pragma unroll
    for (int mt = 0; mt < 2; ++mt) {
#pragma unroll
        for (int rg = 0; rg < 4; ++rg) {
            int o0 = mt * 32 + rg * 8 + kg * 4;
            f32x4 bv = *(const f32x4*)(b1l + o0);
            half4_t hv;
#pragma unroll
            for (int j = 0; j < 4; ++j)
                hv[j] = (_Float16)fmaxf(acc[mt][rg * 4 + j] + bv[j], 0.f);
            *(half4_t*)(mrow + o0) = hv;
        }
    }
    __syncthreads();

    // channel mix (K=64)
    f32x16 acc2[2];
#pragma unroll
    for (int mt = 0; mt < 2; ++mt)
#pragma unroll
        for (int r = 0; r < 16; ++r) acc2[mt][r] = 0.f;
#pragma unroll
    for (int ks = 0; ks < 4; ++ks) {
        int i8 = ks * 2 + kg;
        half8_t a0 = gl[i8 * H_ + ln31];
        half8_t a1 = gl[i8 * H_ + 32 + ln31];
        half8_t b0 = ld_b8(mrow + i8 * 8);
        acc2[0] = __builtin_amdgcn_mfma_f32_32x32x16_f16(a0, b0, acc2[0], 0, 0, 0);
        acc2[1] = __builtin_amdgcn_mfma_f32_32x32x16_f16(a1, b0, acc2[1], 0, 0, 0);
    }

    // write acc2 -> mid rows (wave-own), then coalesced b128 copy-out
#pragma unroll
    for (int mt = 0; mt < 2; ++mt) {
#pragma unroll
        for (int rg = 0; rg < 4; ++rg) {
            int o0 = mt * 32 + rg * 8 + kg * 4;
            half4_t hv;
#pragma unroll
            for (int j = 0; j < 4; ++j)
                hv[j] = (_Float16)acc2[mt][rg * 4 + j];
            *(half4_t*)(mrow + o0) = hv;
        }
    }
    __syncthreads();
    _Float16* gout = supb + (size_t)(tc * 128) * H_;
    const _Float16* srow = Xs + 4 * 68;
#pragma unroll
    for (int k2 = 0; k2 < 4; ++k2) {
        int u = k2 * 256 + tid;     // 1024 units: 128 rows x 8 col-groups
        int r = u >> 3, c = u & 7;
        half8_t v = ld_b8(srow + r * 68 + c * 8);
        *(half8_t*)(gout + (size_t)r * H_ + c * 8) = v;
    }
}

// ---------------- prep: fold BN into conv W; gcw pack; adj pad; zero p1/feat ----------------
__global__ __launch_bounds__(256) void prep_k(Args A) {
    int blk = blockIdx.x;
    int tid = threadIdx.x;
    if (blk < 1728) {                       // conv-weight fold: 4 sets x 432 blocks
        int set = blk / 432;
        int bx = blk % 432;
        ConvPrepSet s = (set == 0) ? A.sb1 : (set == 1) ? A.sb2 : (set == 2) ? A.sf1 : A.sf2;
        int idx = bx * 256 + tid;           // < 110592
        int k = idx % K_; int r = idx / K_;
        int i = r % H_; r /= H_;
        int o = r % H_; int l = r / H_;
        float sc = s.g[l * H_ + o] * rsqrtf(s.v[l * H_ + o] + 1e-5f);
        A.W3[(size_t)set * 110592 + ((((l * K_ + k) * 8 + (i >> 3)) * H_ + o) * 8) + (i & 7)]
            = (_Float16)(s.w[idx] * sc);
        if (i == 0 && k == 0)
            A.B2[set * 192 + l * H_ + o] =
                s.tb[l * H_ + o] * sc + s.bb[l * H_ + o] - s.m[l * H_ + o] * sc;
    } else if (blk < 1824) {                // gc-weight pack: 2 sets x 48 blocks
        int set = (blk - 1728) / 48;
        int bx = (blk - 1728) % 48;
        const float* gw = set ? A.f_gcw : A.b_gcw;
        int idx = bx * 256 + tid;           // < 12288
        int o = idx % H_; int r = idx / H_;
        int c = r % H_; int l = r / H_;
        A.GW3[(size_t)set * 12288 + (((l * 8 + (c >> 3)) * H_ + o) * 8) + (c & 7)]
            = (_Float16)gw[idx];
    } else {                                // misc: adj pad + zero p1/feat
        int idx = (blk - 1824) * 256 + tid;
        if (idx < 1024) {
            int m = idx >> 5, k = idx & 31;
            A.adjPB[idx] = (m < NB_ && k < NB_) ? (_Float16)A.body_adj[m * NB_ + k] : (_Float16)0.f;
        } else if (idx < 8704) {
            int j = idx - 1024;
            int m = j / 80, k = j % 80;
            A.adjPF[j] = (m < NF_ && k < NF_) ? (_Float16)A.face_adj[m * NF_ + k] : (_Float16)0.f;
        } else if (idx < 10752) {
            A.p1[idx - 8704] = 0.f;
        } else if (idx < 10752 + B_ * FEAT_DIM) {
            A.feat[idx - 10752] = 0.f;
        }
    }
}

// ---------------- fused proj + convmix(l=0), chunked: block = (bn, t-chunk) ----------------
__global__ __launch_bounds__(256, 4) void projcm_k(Args A) {
    __shared__ __align__(16) _Float16 Xs[136 * 68];
    int blk = blockIdx.x, tid = threadIdx.x;
    bool isB = blk < 2 * B_ * NB_;
    int j = isB ? blk : blk - 2 * B_ * NB_;
    int bn = j >> 1, tc = j & 1;
    const float* kps = isB ? A.body_kps : A.face_kps;
    const float* pw  = isB ? A.body_pw  : A.face_pw;
    const float* pb  = isB ? A.body_pb  : A.face_pb;
    _Float16* trunk  = isB ? A.TrB : A.TrF;
    int N = isB ? NB_ : NF_;
    int b = bn / N, n = bn % N;

    // proj: fill Xs rows 0..135 (incl. halo recompute); global write for owned rows only
    for (int u = tid; u < 272; u += 256) {
        int row = u >> 1, hf = u & 1;       // 32 channels per unit
        int t = tc * 128 + row - 4;
        _Float16* xr = Xs + row * 68 + hf * 32;
        if (t >= 0 && t < T_) {
            float x0 = kps[((size_t)b * T_ + t) * (N * 2) + n * 2 + 0];
            float x1 = kps[((size_t)b * T_ + t) * (N * 2) + n * 2 + 1];
            bool own = (row >= 4 && row < 132);
            _Float16* ob = trunk + (size_t)bn * HT + (size_t)t * H_ + hf * 32;
#pragma unroll
            for (int cg2 = 0; cg2 < 4; ++cg2) {
                half8_t v;
#pragma unroll
                for (int jj = 0; jj < 8; ++jj) {
                    int c = hf * 32 + cg2 * 8 + jj;
                    v[jj] = (_Float16)fmaf(x0, pw[c], fmaf(x1, pw[H_ + c], pb[c]));
                }
                st_b8(xr + cg2 * 8, v);
                if (own) *(half8_t*)(ob + cg2 * 8) = v;
            }
        } else {
            half8_t z;
#pragma unroll
            for (int jj = 0; jj < 8; ++jj) z[jj] = (_Float16)0.f;
            st_b8(xr, z);
            st_b8(xr + 8, z);
            st_b8(xr + 16, z);
            st_b8(xr + 24, z);
        }
    }
    __syncthreads();

    const half8_t* w1 = (const half8_t*)(A.W3 + (isB ? 0 : 221184));     // l=0 slice
    const float* b1l  = isB ? A.B2 : A.B2 + 384;
    const half8_t* gl = (const half8_t*)(A.GW3 + (isB ? 0 : 12288));
    _Float16* supb = (isB ? A.SupB : A.SupF) + (size_t)bn * HT;
    convmix_core(w1, b1l, gl, supb, tc, Xs, tid);
}

// ---------------- convmix(l), chunked: trunk -> sup ----------------
__global__ __launch_bounds__(256, 4) void cm_k(Args A, int l) {
    __shared__ __align__(16) _Float16 Xs[136 * 68];
    int blk = blockIdx.x, tid = threadIdx.x;
    bool isB = blk < 2 * B_ * NB_;
    int j = isB ? blk : blk - 2 * B_ * NB_;
    int bn = j >> 1, tc = j & 1;
    const _Float16* trunk = isB ? A.TrB : A.TrF;

    stage_chunk(trunk + (size_t)bn * HT, Xs, tc, tid);
    __syncthreads();

    const half8_t* w1 = (const half8_t*)(A.W3 + (isB ? 0 : 221184)) + (size_t)l * (K_ * 8 * H_);
    const float* b1l  = (isB ? A.B2 : A.B2 + 384) + l * H_;
    const half8_t* gl = (const half8_t*)(A.GW3 + (isB ? 0 : 12288)) + (size_t)l * (8 * H_);
    _Float16* supb = (isB ? A.SupB : A.SupF) + (size_t)bn * HT;
    convmix_core(w1, b1l, gl, supb, tc, Xs, tid);
}

// ---------------- adjmix: out = relu(adj @ sup + gb), LDS-transposed b128 output ----------------
template <int N, int MT, int KS>
__device__ void adjmix_impl(const _Float16* __restrict__ sup,
                            const half8_t* __restrict__ adjP,
                            const float* __restrict__ gb,
                            _Float16* __restrict__ out,
                            int blk, int l, _Float16* Ls, int tid) {
    constexpr int KP = KS * 16;
    constexpr int PITCH = KP + 4;
    int b = blk >> 7, cb = blk & 127;
    int colbase = cb * 128;

    for (int u = tid; u < KP * 16; u += 256) {
        int n = u >> 4, cs = u & 15;
        half8_t v;
        if (n < N) v = *(const half8_t*)(sup + (size_t)(b * N + n) * HT + colbase + cs * 8);
        else {
#pragma unroll
            for (int j = 0; j < 8; ++j) v[j] = (_Float16)0.f;
        }
#pragma unroll
        for (int j = 0; j < 8; ++j) Ls[(cs * 8 + j) * PITCH + n] = v[j];
    }
    __syncthreads();

    int ln = tid & 63;
    int w = __builtin_amdgcn_readfirstlane(tid >> 6);
    int ln31 = ln & 31, kg = ln >> 5;
    int colL = w * 32 + ln31;

    f32x16 acc[MT];
#pragma unroll
    for (int mt = 0; mt < MT; ++mt)
#pragma unroll
        for (int r = 0; r < 16; ++r) acc[mt][r] = 0.f;

#pragma unroll
    for (int ks = 0; ks < KS; ++ks) {
        half8_t bf = ld_b8(&Ls[colL * PITCH + ks * 16 + kg * 8]);
#pragma unroll
        for (int mt = 0; mt < MT; ++mt) {
            half8_t af = adjP[(size_t)(mt * 32 + ln31) * (KP / 8) + ks * 2 + kg];
            acc[mt] = __builtin_amdgcn_mfma_f32_32x32x16_f16(af, bf, acc[mt], 0, 0, 0);
        }
    }
    __syncthreads();   // staging reads done; reuse Ls as [m][132] out-transpose buffer

    float gbv = gb[l * H_ + (colL & 63)];   // [t][o] layout: o = col & 63
#pragma unroll
    for (int mt = 0; mt < MT; ++mt) {
#pragma unroll
        for (int r = 0; r < 16; ++r) {
            int m = mt * 32 + (r & 3) + 8 * (r >> 2) + 4 * kg;
            Ls[m * 132 + colL] = (_Float16)fmaxf(acc[mt][r] + gbv, 0.f);
        }
    }
    __syncthreads();

    for (int u = tid; u < N * 16; u += 256) {
        int m = u >> 4, c = u & 15;
        half8_t v = ld_b8(&Ls[m * 132 + c * 8]);
        *(half8_t*)(out + (size_t)(b * N + m) * HT + colbase + c * 8) = v;
    }
}

__global__ __launch_bounds__(256) void adjmix_k(Args A, int l) {
    __shared__ __align__(16) _Float16 Ls[12800];
    int blk = blockIdx.x, tid = threadIdx.x;
    if (blk < 1024)
        adjmix_impl<NB_, 1, 2>(A.SupB, (const half8_t*)A.adjPB, A.b_gcb, A.Gb, blk, l, Ls, tid);
    else
        adjmix_impl<NF_, 3, 5>(A.SupF, (const half8_t*)A.adjPF, A.f_gcb, A.Gf, blk - 1024, l, Ls, tid);
}

// ---------------- conv2(l)(+bn+res), chunked: G -> trunk ----------------
__global__ __launch_bounds__(256, 4) void c2_k(Args A, int l) {
    __shared__ __align__(16) _Float16 Xs[136 * 68];
    __shared__ __align__(16) _Float16 Rs[128 * 68];
    int blk = blockIdx.x, tid = threadIdx.x;
    bool isB = blk < 2 * B_ * NB_;
    int j = isB ? blk : blk - 2 * B_ * NB_;
    int bn = j >> 1, tc = j & 1;
    const _Float16* G = isB ? A.Gb : A.Gf;
    _Float16* trunk   = isB ? A.TrB : A.TrF;
    const half8_t* w2 = (const half8_t*)(A.W3 + (isB ? 110592 : 331776)) + (size_t)l * (K_ * 8 * H_);
    const float* b2l  = (isB ? A.B2 + 192 : A.B2 + 576) + l * H_;

    stage_chunk(G + (size_t)bn * HT, Xs, tc, tid);
    stage_res_chunk(trunk + (size_t)bn * HT, Rs, tc, tid);
    __syncthreads();

    int ln = tid & 63;
    int w = __builtin_amdgcn_readfirstlane(tid >> 6);
    int ln31 = ln & 31, kg = ln >> 5;
    int trow = w * 32;

    f32x16 acc[2];
#pragma unroll
    for (int mt = 0; mt < 2; ++mt)
#pragma unroll
        for (int r = 0; r < 16; ++r) acc[mt][r] = 0.f;

    conv_kloop(w2, Xs, trow, ln31, kg, acc);
    __syncthreads();   // all conv B-reads done before overwriting Xs rows

    // epilogue: y = acc + b2 + res -> Xs[4+t][o] (f16, same rounding as before)
    {
        _Float16* orow = Xs + (size_t)(4 + trow + ln31) * 68;
        const _Float16* rrow = Rs + (size_t)(trow + ln31) * 68;
#pragma unroll
        for (int mt = 0; mt < 2; ++mt) {
#pragma unroll
            for (int rg = 0; rg < 4; ++rg) {
                int o0 = mt * 32 + rg * 8 + kg * 4;
                f32x4 bv = *(const f32x4*)(b2l + o0);
                half4_t rv = *(const half4_t*)(rrow + o0);
                half4_t hv;
#pragma unroll
                for (int jj = 0; jj < 4; ++jj)
                    hv[jj] = (_Float16)(acc[mt][rg * 4 + jj] + bv[jj] + (float)rv[jj]);
                *(half4_t*)(orow + o0) = hv;
            }
        }
    }
    __syncthreads();

    // copy new trunk chunk out
    _Float16* gout = trunk + (size_t)bn * HT + (size_t)(tc * 128) * H_;
    const _Float16* srow = Xs + 4 * 68;
#pragma unroll
    for (int k2 = 0; k2 < 4; ++k2) {
        int u = k2 * 256 + tid;
        int r = u >> 3, c = u & 7;
        half8_t v = ld_b8(srow + r * 68 + c * 8);
        *(half8_t*)(gout + (size_t)r * H_ + c * 8) = v;
    }
}

// ---------------- conv2(2,LAST), chunked: mean-pool partial -> feat; tail blocks = head ----------------
__global__ __launch_bounds__(256, 4) void c2last_k(Args A) {
    __shared__ __align__(16) _Float16 Xs[136 * 68];
    __shared__ __align__(16) _Float16 Rs[128 * 68];
    int blk = blockIdx.x, tid = threadIdx.x;
    if (blk >= 1360) {             // head stream: 8 blocks
        int b = blk - 1360;
        if (tid < 64) {
            int c = tid;
            float w0 = A.head_w[c], w1 = A.head_w[64 + c], w2 = A.head_w[128 + c],
                  w3 = A.head_w[192 + c], w4 = A.head_w[256 + c], w5 = A.head_w[320 + c];
            float bias = A.head_b[c];
            float acc = 0.f;
            for (int t = 0; t < T_; ++t) {
                const float* xr = A.head_pose + ((size_t)b * T_ + t) * HP_;
                float s = fmaf(xr[0], w0, fmaf(xr[1], w1, fmaf(xr[2], w2,
                          fmaf(xr[3], w3, fmaf(xr[4], w4, fmaf(xr[5], w5, bias))))));
                acc += fmaxf(s, 0.f);
            }
            A.feat[(size_t)b * FEAT_DIM + NB_ * H_ + NF_ * H_ + c] = acc * (1.f / 256.f);
        }
        return;
    }
    constexpr int l = L_ - 1;
    bool isB = blk < 2 * B_ * NB_;
    int j = isB ? blk : blk - 2 * B_ * NB_;
    int bn = j >> 1, tc = j & 1;
    const _Float16* G = isB ? A.Gb : A.Gf;
    _Float16* trunk   = isB ? A.TrB : A.TrF;
    const half8_t* w2 = (const half8_t*)(A.W3 + (isB ? 110592 : 331776)) + (size_t)l * (K_ * 8 * H_);
    const float* b2l  = (isB ? A.B2 + 192 : A.B2 + 576) + l * H_;
    int N = isB ? NB_ : NF_;
    int fbase = isB ? 0 : NB_ * H_;

    stage_chunk(G + (size_t)bn * HT, Xs, tc, tid);
    stage_res_chunk(trunk + (size_t)bn * HT, Rs, tc, tid);
    __syncthreads();

    int ln = tid & 63;
    int w = __builtin_amdgcn_readfirstlane(tid >> 6);
    int ln31 = ln & 31, kg = ln >> 5;
    int trow = w * 32;

    f32x16 acc[2];
#pragma unroll
    for (int mt = 0; mt < 2; ++mt)
#pragma unroll
        for (int r = 0; r < 16; ++r) acc[mt][r] = 0.f;

    conv_kloop(w2, Xs, trow, ln31, kg, acc);

    // mean-pool partial over this chunk's 128 t: per wave sum 32 t via shfl
    float sv[2][16];
    const _Float16* rrow = Rs + (size_t)(trow + ln31) * 68;
#pragma unroll
    for (int mt = 0; mt < 2; ++mt) {
#pragma unroll
        for (int rg = 0; rg < 4; ++rg) {
            int o0 = mt * 32 + rg * 8 + kg * 4;
            f32x4 bv = *(const f32x4*)(b2l + o0);
            half4_t rv = *(const half4_t*)(rrow + o0);
#pragma unroll
            for (int jj = 0; jj < 4; ++jj) {
                int r = rg * 4 + jj;
                float s = acc[mt][r] + bv[jj] + (float)rv[jj];
#pragma unroll
                for (int off = 1; off < 32; off <<= 1) s += __shfl_xor(s, off);
                sv[mt][r] = s;
            }
        }
    }
    __syncthreads();   // Xs reads done; reuse as reduction scratch
    float* red = (float*)Xs;
    if (ln31 == 0) {
#pragma unroll
        for (int mt = 0; mt < 2; ++mt)
#pragma unroll
            for (int r = 0; r < 16; ++r) {
                int o = mt * 32 + (r & 3) + 8 * (r >> 2) + 4 * kg;
                red[w * 64 + o] = sv[mt][r];
            }
    }
    __syncthreads();
    if (tid < 64) {
        float s = red[tid] + red[64 + tid] + red[128 + tid] + red[192 + tid];
        int b = bn / N, n = bn % N;
        atomicAdd(&A.feat[(size_t)b * FEAT_DIM + fbase + n * H_ + tid], s * (1.f / 256.f));
    }
}

// ---------------- fusion layer 1 (5504 -> 256), split-K, all 8 batches per block ----------------
__global__ __launch_bounds__(256) void fus1_k(Args A) {
    __shared__ float fv[8][64];
    int blk = blockIdx.x;          // 86 = 43 ic * 2 khalf
    int ic = blk >> 1, kh = blk & 1;
    int base = ic * 128 + kh * 64;
    int tid = threadIdx.x;
    for (int u = tid; u < 8 * 64; u += 256) {
        int b = u >> 6, j = u & 63;
        fv[b][j] = A.feat[(size_t)b * FEAT_DIM + base + j];
    }
    __syncthreads();
    float acc[8];
#pragma unroll
    for (int b = 0; b < 8; ++b) acc[b] = 0.f;
    const float* wb = A.fus1_w + (size_t)base * 256 + tid;
    for (int i = 0; i < 64; ++i) {
        float wv = wb[(size_t)i * 256];
#pragma unroll
        for (int b = 0; b < 8; ++b) acc[b] = fmaf(fv[b][i], wv, acc[b]);
    }
#pragma unroll
    for (int b = 0; b < 8; ++b) atomicAdd(&A.p1[b * 256 + tid], acc[b]);
}

// ---------------- fusion tail ----------------
__global__ __launch_bounds__(256) void fus_tail_k(Args A) {
    __shared__ float s1[256], s2[128], s3[64];
    int b = blockIdx.x, tid = threadIdx.x;
    s1[tid] = fmaxf(A.p1[b * 256 + tid] + A.fus1_b[tid], 0.f);
    __syncthreads();
    if (tid < 128) {
        float acc = A.fus2_b[tid];
        for (int i = 0; i < 256; ++i) acc = fmaf(s1[i], A.fus2_w[i * 128 + tid], acc);
        s2[tid] = fmaxf(acc, 0.f);
    }
    __syncthreads();
    if (tid < 64) {
        float acc = A.fus3_b[tid];
        for (int i = 0; i < 128; ++i) acc = fmaf(s2[i], A.fus3_w[i * 64 + tid], acc);
        s3[tid] = fmaxf(acc, 0.f);
    }
    __syncthreads();
    if (tid < 5) {
        float acc = A.fus4_b[tid];
        for (int i = 0; i < 64; ++i) acc = fmaf(s3[i], A.fus4_w[i * 5 + tid], acc);
        A.out[b * 5 + tid] = acc;
    }
}

// ---------------- launch ----------------
extern "C" void kernel_launch(void* const* d_in, const int* in_sizes, int n_in,
                              void* d_out, int out_size, void* d_ws, size_t ws_size,
                              hipStream_t stream) {
    float* ws = (float*)d_ws;

    Args A;
    A.body_kps = (const float*)d_in[0];
    A.face_kps = (const float*)d_in[1];
    A.head_pose = (const float*)d_in[2];
    A.body_adj = (const float*)d_in[3];
    A.face_adj = (const float*)d_in[4];
    A.body_pw = (const float*)d_in[5];
    A.body_pb = (const float*)d_in[6];
    A.face_pw = (const float*)d_in[7];
    A.face_pb = (const float*)d_in[8];
    A.head_w = (const float*)d_in[9];
    A.head_b = (const float*)d_in[10];
    A.sb1 = ConvPrepSet{(const float*)d_in[11], (const float*)d_in[12], (const float*)d_in[13],
                        (const float*)d_in[14], (const float*)d_in[15], (const float*)d_in[16]};
    A.b_gcw = (const float*)d_in[17];
    A.b_gcb = (const float*)d_in[18];
    A.sb2 = ConvPrepSet{(const float*)d_in[19], (const float*)d_in[20], (const float*)d_in[21],
                        (const float*)d_in[22], (const float*)d_in[23], (const float*)d_in[24]};
    A.sf1 = ConvPrepSet{(const float*)d_in[25], (const float*)d_in[26], (const float*)d_in[27],
                        (const float*)d_in[28], (const float*)d_in[29], (const float*)d_in[30]};
    A.f_gcw = (const float*)d_in[31];
    A.f_gcb = (const float*)d_in[32];
    A.sf2 = ConvPrepSet{(const float*)d_in[33], (const float*)d_in[34], (const float*)d_in[35],
                        (const float*)d_in[36], (const float*)d_in[37], (const float*)d_in[38]};
    A.fus1_w = (const float*)d_in[39]; A.fus1_b = (const float*)d_in[40];
    A.fus2_w = (const float*)d_in[41]; A.fus2_b = (const float*)d_in[42];
    A.fus3_w = (const float*)d_in[43]; A.fus3_b = (const float*)d_in[44];
    A.fus4_w = (const float*)d_in[45]; A.fus4_b = (const float*)d_in[46];

    A.TrB  = (_Float16*)(ws + OFF_TB);
    A.TrF  = (_Float16*)(ws + OFF_TF);
    A.SupB = (_Float16*)(ws + OFF_SUPB);
    A.SupF = (_Float16*)(ws + OFF_SUPF);
    A.Gb   = (_Float16*)(ws + OFF_GB);
    A.Gf   = (_Float16*)(ws + OFF_GF);
    A.W3   = (_Float16*)(ws + OFF_W3);
    A.GW3  = (_Float16*)(ws + OFF_GW3);
    A.adjPB= (_Float16*)(ws + OFF_ADJPB);
    A.adjPF= (_Float16*)(ws + OFF_ADJPF);
    A.B2   = ws + OFF_B2;
    A.feat = ws + OFF_FEAT;
    A.p1   = ws + OFF_P1;
    A.out  = (float*)d_out;

    prep_k<<<2038, 256, 0, stream>>>(A);
    projcm_k<<<1360, 256, 0, stream>>>(A);            // proj + convmix(0), chunked
    for (int l = 0; l < L_; ++l) {
        adjmix_k<<<2048, 256, 0, stream>>>(A, l);
        if (l < L_ - 1) {
            c2_k<<<1360, 256, 0, stream>>>(A, l);     // conv2(l), chunked
            cm_k<<<1360, 256, 0, stream>>>(A, l + 1); // convmix(l+1), chunked
        } else {
            c2last_k<<<1368, 256, 0, stream>>>(A);    // conv2(2)+pool + head
        }
    }
    fus1_k<<<86, 256, 0, stream>>>(A);
    fus_tail_k<<<8, 256, 0, stream>>>(A);
}

// Round 6
// 369.607 us; speedup vs baseline: 5.7223x; 1.0359x over previous
//
#include <hip/hip_runtime.h>

// ---------------- problem constants ----------------
constexpr int B_ = 8, T_ = 256, H_ = 64, L_ = 3, NB_ = 17, NF_ = 68, HP_ = 6, K_ = 9;
constexpr int FEAT_DIM = NB_ * H_ + NF_ * H_ + H_;   // 5504
constexpr int HT = H_ * T_;                          // 16384 per (b,n)

typedef _Float16 half4_t __attribute__((ext_vector_type(4)));
typedef _Float16 half8_t __attribute__((ext_vector_type(8)));
typedef float f32x16 __attribute__((ext_vector_type(16)));
typedef float f32x4 __attribute__((ext_vector_type(4)));

// ---------------- workspace layout (float units); activations f16 [bn][t][o] ----------------
constexpr size_t SZ_AB = (size_t)B_ * NB_ * HT;
constexpr size_t SZ_AF = (size_t)B_ * NF_ * HT;
constexpr size_t OFF_TB   = 0;
constexpr size_t OFF_TF   = OFF_TB + SZ_AB / 2;
constexpr size_t OFF_SUPB = OFF_TF + SZ_AF / 2;
constexpr size_t OFF_SUPF = OFF_SUPB + SZ_AB / 2;
constexpr size_t OFF_GB   = OFF_SUPF + SZ_AF / 2;
constexpr size_t OFF_GF   = OFF_GB + SZ_AB / 2;
constexpr size_t OFF_W3   = OFF_GF + SZ_AF / 2;      // 4 conv sets x 110592 f16
constexpr size_t OFF_GW3  = OFF_W3 + 4 * 55296;      // 2 x 12288 f16
constexpr size_t OFF_B2   = OFF_GW3 + 2 * 6144;      // 4 x 192 f32
constexpr size_t OFF_ADJPB= OFF_B2 + 768;            // 32x32 f16
constexpr size_t OFF_ADJPF= OFF_ADJPB + 512;         // 96x80 f16
constexpr size_t OFF_FEAT = OFF_ADJPF + 3840;        // 8x5504 f32
constexpr size_t OFF_P1   = OFF_FEAT + (size_t)B_ * FEAT_DIM;

struct ConvPrepSet { const float *w, *tb, *g, *bb, *m, *v; };

// ---------------- all pointers in one arg struct ----------------
struct Args {
    const float *body_kps, *face_kps, *head_pose, *body_adj, *face_adj;
    const float *body_pw, *body_pb, *face_pw, *face_pb, *head_w, *head_b;
    ConvPrepSet sb1, sb2, sf1, sf2;
    const float *b_gcw, *f_gcw, *b_gcb, *f_gcb;
    const float *fus1_w, *fus1_b, *fus2_w, *fus2_b, *fus3_w, *fus3_b, *fus4_w, *fus4_b;
    _Float16 *TrB, *TrF, *SupB, *SupF, *Gb, *Gf;
    _Float16 *W3, *GW3, *adjPB, *adjPF;
    float *B2, *p1, *feat;
    float *out;
};

// ---------------- small helpers ----------------
__device__ __forceinline__ half8_t ld_b8(const _Float16* p) {
    half4_t lo = *(const half4_t*)p;
    half4_t hi = *(const half4_t*)(p + 4);
    return __builtin_shufflevector(lo, hi, 0, 1, 2, 3, 4, 5, 6, 7);
}

__device__ __forceinline__ void st_b8(_Float16* p, half8_t v) {
    half4_t lo, hi;
#pragma unroll
    for (int j = 0; j < 4; ++j) { lo[j] = v[j]; hi[j] = v[4 + j]; }
    *(half4_t*)p = lo;
    *(half4_t*)(p + 4) = hi;
}

// stage f16 [t][o] 64-t chunk -> Xs[72][68]; rows 0..71 = t (tc*64-4 .. tc*64+67), OOB=0
__device__ __forceinline__ void stage_chunk64(const _Float16* __restrict__ xb,
                                              _Float16* __restrict__ Xs, int tc, int tid) {
    for (int u = tid; u < 72 * 8; u += 256) {
        int row = u >> 3, c = u & 7;
        int t = tc * 64 + row - 4;
        half8_t v;
        if (t >= 0 && t < T_) {
            v = *(const half8_t*)(xb + (size_t)t * H_ + c * 8);
        } else {
#pragma unroll
            for (int j = 0; j < 8; ++j) v[j] = (_Float16)0.f;
        }
        st_b8(&Xs[row * 68 + c * 8], v);
    }
}

// stage residual 64-t chunk rows [t][o] -> Rs[64][68] (t = tc*64 .. tc*64+63)
__device__ __forceinline__ void stage_res64(const _Float16* __restrict__ xb,
                                            _Float16* __restrict__ Rs, int tc, int tid) {
    for (int u = tid; u < 64 * 8; u += 256) {
        int row = u >> 3, c = u & 7;
        half8_t v = *(const half8_t*)(xb + (size_t)(tc * 64 + row) * H_ + c * 8);
        st_b8(&Rs[row * 68 + c * 8], v);
    }
}

// conv K-loop: 9 taps x 4 ks -> acc, wave covers 32 t-cols x 32 o (one o-tile)
__device__ __forceinline__ void conv_kloop(const half8_t* __restrict__ wl,
                                           const _Float16* __restrict__ Xs,
                                           int trow, int ln31, int kg, int ot,
                                           f32x16& acc) {
    const _Float16* xr0 = Xs + (size_t)(trow + ln31) * 68;
#pragma unroll
    for (int tap = 0; tap < K_; ++tap) {
#pragma unroll
        for (int ks = 0; ks < 4; ++ks) {
            int i8 = ks * 2 + kg;
            half8_t a = wl[(tap * 8 + i8) * H_ + ot * 32 + ln31];
            half8_t bf = ld_b8(xr0 + tap * 68 + i8 * 8);
            acc = __builtin_amdgcn_mfma_f32_32x32x16_f16(a, bf, acc, 0, 0, 0);
        }
    }
}

// ---------------- convmix core: Xs pre-staged -> sup 64-t chunk ----------------
// 4 waves: wave (ts = w&1, ot = w>>1) covers t-sub 32ts..32ts+32, o-tile 32ot..
__device__ void convmix_core(const half8_t* __restrict__ wl,   // w1 + layer offset
                             const float* __restrict__ b1l,    // b1 + l*H_
                             const half8_t* __restrict__ gl,   // gc + layer offset
                             _Float16* __restrict__ supb,      // sup + bn*HT
                             int tc, _Float16* __restrict__ Xs, int tid) {
    int ln = tid & 63;
    int w = __builtin_amdgcn_readfirstlane(tid >> 6);
    int ln31 = ln & 31, kg = ln >> 5;
    int ts = w & 1, ot = w >> 1;
    int trow = ts * 32;

    f32x16 acc;
#pragma unroll
    for (int r = 0; r < 16; ++r) acc[r] = 0.f;

    conv_kloop(wl, Xs, trow, ln31, kg, ot, acc);
    __syncthreads();

    // conv1 epilogue: bias+relu -> mid row Xs[4+t][o] (wave-own (ts,ot) region)
    _Float16* mrow = Xs + (size_t)(4 + trow + ln31) * 68;
#pragma unroll
    for (int rg = 0; rg < 4; ++rg) {
        int o0 = ot * 32 + rg * 8 + kg * 4;
        f32x4 bv = *(const f32x4*)(b1l + o0);
        half4_t hv;
#pragma unroll
        for (int j = 0; j < 4; ++j)
            hv[j] = (_Float16)fmaxf(acc[rg * 4 + j] + bv[j], 0.f);
        *(half4_t*)(mrow + o0) = hv;
    }
    __syncthreads();

    // channel mix (K=64): reads full mid rows (both o-halves)
    f32x16 acc2;
#pragma unroll
    for (int r = 0; r < 16; ++r) acc2[r] = 0.f;
#pragma unroll
    for (int ks = 0; ks < 4; ++ks) {
        int i8 = ks * 2 + kg;
        half8_t a = gl[i8 * H_ + ot * 32 + ln31];
        half8_t bf = ld_b8(mrow + i8 * 8);
        acc2 = __builtin_amdgcn_mfma_f32_32x32x16_f16(a, bf, acc2, 0, 0, 0);
    }
    __syncthreads();   // other o-wave may still be reading these rows

    // write acc2 -> mid rows (wave-own region), then coalesced b128 copy-out
#pragma unroll
    for (int rg = 0; rg < 4; ++rg) {
        int o0 = ot * 32 + rg * 8 + kg * 4;
        half4_t hv;
#pragma unroll
        for (int j = 0; j < 4; ++j)
            hv[j] = (_Float16)acc2[rg * 4 + j];
        *(half4_t*)(mrow + o0) = hv;
    }
    __syncthreads();
    _Float16* gout = supb + (size_t)(tc * 64) * H_;
    const _Float16* srow = Xs + 4 * 68;
#pragma unroll
    for (int k2 = 0; k2 < 2; ++k2) {
        int u = k2 * 256 + tid;     // 512 units: 64 rows x 8 col-groups
        int r = u >> 3, c = u & 7;
        half8_t v = ld_b8(srow + r * 68 + c * 8);
        *(half8_t*)(gout + (size_t)r * H_ + c * 8) = v;
    }
}

// ---------------- prep: fold BN into conv W; gcw pack; adj pad; zero p1/feat ----------------
__global__ __launch_bounds__(256) void prep_k(Args A) {
    int blk = blockIdx.x;
    int tid = threadIdx.x;
    if (blk < 1728) {                       // conv-weight fold: 4 sets x 432 blocks
        int set = blk / 432;
        int bx = blk % 432;
        ConvPrepSet s = (set == 0) ? A.sb1 : (set == 1) ? A.sb2 : (set == 2) ? A.sf1 : A.sf2;
        int idx = bx * 256 + tid;           // < 110592
        int k = idx % K_; int r = idx / K_;
        int i = r % H_; r /= H_;
        int o = r % H_; int l = r / H_;
        float sc = s.g[l * H_ + o] * rsqrtf(s.v[l * H_ + o] + 1e-5f);
        A.W3[(size_t)set * 110592 + ((((l * K_ + k) * 8 + (i >> 3)) * H_ + o) * 8) + (i & 7)]
            = (_Float16)(s.w[idx] * sc);
        if (i == 0 && k == 0)
            A.B2[set * 192 + l * H_ + o] =
                s.tb[l * H_ + o] * sc + s.bb[l * H_ + o] - s.m[l * H_ + o] * sc;
    } else if (blk < 1824) {                // gc-weight pack: 2 sets x 48 blocks
        int set = (blk - 1728) / 48;
        int bx = (blk - 1728) % 48;
        const float* gw = set ? A.f_gcw : A.b_gcw;
        int idx = bx * 256 + tid;           // < 12288
        int o = idx % H_; int r = idx / H_;
        int c = r % H_; int l = r / H_;
        A.GW3[(size_t)set * 12288 + (((l * 8 + (c >> 3)) * H_ + o) * 8) + (c & 7)]
            = (_Float16)gw[idx];
    } else {                                // misc: adj pad + zero p1/feat
        int idx = (blk - 1824) * 256 + tid;
        if (idx < 1024) {
            int m = idx >> 5, k = idx & 31;
            A.adjPB[idx] = (m < NB_ && k < NB_) ? (_Float16)A.body_adj[m * NB_ + k] : (_Float16)0.f;
        } else if (idx < 8704) {
            int j = idx - 1024;
            int m = j / 80, k = j % 80;
            A.adjPF[j] = (m < NF_ && k < NF_) ? (_Float16)A.face_adj[m * NF_ + k] : (_Float16)0.f;
        } else if (idx < 10752) {
            A.p1[idx - 8704] = 0.f;
        } else if (idx < 10752 + B_ * FEAT_DIM) {
            A.feat[idx - 10752] = 0.f;
        }
    }
}

// ---------------- fused proj + convmix(l=0): block = (bn, 64-t chunk) ----------------
__global__ __launch_bounds__(256, 8) void projcm_k(Args A) {
    __shared__ __align__(16) _Float16 Xs[72 * 68];
    int blk = blockIdx.x, tid = threadIdx.x;
    bool isB = blk < 4 * B_ * NB_;
    int j = isB ? blk : blk - 4 * B_ * NB_;
    int bn = j >> 2, tc = j & 3;
    const float* kps = isB ? A.body_kps : A.face_kps;
    const float* pw  = isB ? A.body_pw  : A.face_pw;
    const float* pb  = isB ? A.body_pb  : A.face_pb;
    _Float16* trunk  = isB ? A.TrB : A.TrF;
    int N = isB ? NB_ : NF_;
    int b = bn / N, n = bn % N;

    // proj: fill Xs rows 0..71 (incl. halo recompute); global write for owned rows only
    if (tid < 144) {
        int row = tid >> 1, hf = tid & 1;       // 32 channels per unit
        int t = tc * 64 + row - 4;
        _Float16* xr = Xs + row * 68 + hf * 32;
        if (t >= 0 && t < T_) {
            float x0 = kps[((size_t)b * T_ + t) * (N * 2) + n * 2 + 0];
            float x1 = kps[((size_t)b * T_ + t) * (N * 2) + n * 2 + 1];
            bool own = (row >= 4 && row < 68);
            _Float16* ob = trunk + (size_t)bn * HT + (size_t)t * H_ + hf * 32;
#pragma unroll
            for (int cg2 = 0; cg2 < 4; ++cg2) {
                half8_t v;
#pragma unroll
                for (int jj = 0; jj < 8; ++jj) {
                    int c = hf * 32 + cg2 * 8 + jj;
                    v[jj] = (_Float16)fmaf(x0, pw[c], fmaf(x1, pw[H_ + c], pb[c]));
                }
                st_b8(xr + cg2 * 8, v);
                if (own) *(half8_t*)(ob + cg2 * 8) = v;
            }
        } else {
            half8_t z;
#pragma unroll
            for (int jj = 0; jj < 8; ++jj) z[jj] = (_Float16)0.f;
            st_b8(xr, z);
            st_b8(xr + 8, z);
            st_b8(xr + 16, z);
            st_b8(xr + 24, z);
        }
    }
    __syncthreads();

    const half8_t* w1 = (const half8_t*)(A.W3 + (isB ? 0 : 221184));     // l=0 slice
    const float* b1l  = isB ? A.B2 : A.B2 + 384;
    const half8_t* gl = (const half8_t*)(A.GW3 + (isB ? 0 : 12288));
    _Float16* supb = (isB ? A.SupB : A.SupF) + (size_t)bn * HT;
    convmix_core(w1, b1l, gl, supb, tc, Xs, tid);
}

// ---------------- convmix(l): trunk -> sup ----------------
__global__ __launch_bounds__(256, 8) void cm_k(Args A, int l) {
    __shared__ __align__(16) _Float16 Xs[72 * 68];
    int blk = blockIdx.x, tid = threadIdx.x;
    bool isB = blk < 4 * B_ * NB_;
    int j = isB ? blk : blk - 4 * B_ * NB_;
    int bn = j >> 2, tc = j & 3;
    const _Float16* trunk = isB ? A.TrB : A.TrF;

    stage_chunk64(trunk + (size_t)bn * HT, Xs, tc, tid);
    __syncthreads();

    const half8_t* w1 = (const half8_t*)(A.W3 + (isB ? 0 : 221184)) + (size_t)l * (K_ * 8 * H_);
    const float* b1l  = (isB ? A.B2 : A.B2 + 384) + l * H_;
    const half8_t* gl = (const half8_t*)(A.GW3 + (isB ? 0 : 12288)) + (size_t)l * (8 * H_);
    _Float16* supb = (isB ? A.SupB : A.SupF) + (size_t)bn * HT;
    convmix_core(w1, b1l, gl, supb, tc, Xs, tid);
}

// ---------------- adjmix: out = relu(adj @ sup + gb), LDS-transposed b128 output ----------------
template <int N, int MT, int KS>
__device__ void adjmix_impl(const _Float16* __restrict__ sup,
                            const half8_t* __restrict__ adjP,
                            const float* __restrict__ gb,
                            _Float16* __restrict__ out,
                            int blk, int l, _Float16* Ls, int tid) {
    constexpr int KP = KS * 16;
    constexpr int PITCH = KP + 4;
    int b = blk >> 7, cb = blk & 127;
    int colbase = cb * 128;

    for (int u = tid; u < KP * 16; u += 256) {
        int n = u >> 4, cs = u & 15;
        half8_t v;
        if (n < N) v = *(const half8_t*)(sup + (size_t)(b * N + n) * HT + colbase + cs * 8);
        else {
#pragma unroll
            for (int j = 0; j < 8; ++j) v[j] = (_Float16)0.f;
        }
#pragma unroll
        for (int j = 0; j < 8; ++j) Ls[(cs * 8 + j) * PITCH + n] = v[j];
    }
    __syncthreads();

    int ln = tid & 63;
    int w = __builtin_amdgcn_readfirstlane(tid >> 6);
    int ln31 = ln & 31, kg = ln >> 5;
    int colL = w * 32 + ln31;

    f32x16 acc[MT];
#pragma unroll
    for (int mt = 0; mt < MT; ++mt)
#pragma unroll
        for (int r = 0; r < 16; ++r) acc[mt][r] = 0.f;

#pragma unroll
    for (int ks = 0; ks < KS; ++ks) {
        half8_t bf = ld_b8(&Ls[colL * PITCH + ks * 16 + kg * 8]);
#pragma unroll
        for (int mt = 0; mt < MT; ++mt) {
            half8_t af = adjP[(size_t)(mt * 32 + ln31) * (KP / 8) + ks * 2 + kg];
            acc[mt] = __builtin_amdgcn_mfma_f32_32x32x16_f16(af, bf, acc[mt], 0, 0, 0);
        }
    }
    __syncthreads();   // staging reads done; reuse Ls as [m][132] out-transpose buffer

    float gbv = gb[l * H_ + (colL & 63)];   // [t][o] layout: o = col & 63
#pragma unroll
    for (int mt = 0; mt < MT; ++mt) {
#pragma unroll
        for (int r = 0; r < 16; ++r) {
            int m = mt * 32 + (r & 3) + 8 * (r >> 2) + 4 * kg;
            Ls[m * 132 + colL] = (_Float16)fmaxf(acc[mt][r] + gbv, 0.f);
        }
    }
    __syncthreads();

    for (int u = tid; u < N * 16; u += 256) {
        int m = u >> 4, c = u & 15;
        half8_t v = ld_b8(&Ls[m * 132 + c * 8]);
        *(half8_t*)(out + (size_t)(b * N + m) * HT + colbase + c * 8) = v;
    }
}

__global__ __launch_bounds__(256) void adjmix_k(Args A, int l) {
    __shared__ __align__(16) _Float16 Ls[12800];
    int blk = blockIdx.x, tid = threadIdx.x;
    if (blk < 1024)
        adjmix_impl<NB_, 1, 2>(A.SupB, (const half8_t*)A.adjPB, A.b_gcb, A.Gb, blk, l, Ls, tid);
    else
        adjmix_impl<NF_, 3, 5>(A.SupF, (const half8_t*)A.adjPF, A.f_gcb, A.Gf, blk - 1024, l, Ls, tid);
}

// ---------------- conv2(l)(+bn+res): G -> trunk ----------------
__global__ __launch_bounds__(256, 8) void c2_k(Args A, int l) {
    __shared__ __align__(16) _Float16 Xs[72 * 68];
    __shared__ __align__(16) _Float16 Rs[64 * 68];
    int blk = blockIdx.x, tid = threadIdx.x;
    bool isB = blk < 4 * B_ * NB_;
    int j = isB ? blk : blk - 4 * B_ * NB_;
    int bn = j >> 2, tc = j & 3;
    const _Float16* G = isB ? A.Gb : A.Gf;
    _Float16* trunk   = isB ? A.TrB : A.TrF;
    const half8_t* w2 = (const half8_t*)(A.W3 + (isB ? 110592 : 331776)) + (size_t)l * (K_ * 8 * H_);
    const float* b2l  = (isB ? A.B2 + 192 : A.B2 + 576) + l * H_;

    stage_chunk64(G + (size_t)bn * HT, Xs, tc, tid);
    stage_res64(trunk + (size_t)bn * HT, Rs, tc, tid);
    __syncthreads();

    int ln = tid & 63;
    int w = __builtin_amdgcn_readfirstlane(tid >> 6);
    int ln31 = ln & 31, kg = ln >> 5;
    int ts = w & 1, ot = w >> 1;
    int trow = ts * 32;

    f32x16 acc;
#pragma unroll
    for (int r = 0; r < 16; ++r) acc[r] = 0.f;

    conv_kloop(w2, Xs, trow, ln31, kg, ot, acc);
    __syncthreads();   // all conv B-reads done before overwriting Xs rows

    // epilogue: y = acc + b2 + res -> Xs[4+t][o] (f16, same rounding as before)
    {
        _Float16* orow = Xs + (size_t)(4 + trow + ln31) * 68;
        const _Float16* rrow = Rs + (size_t)(trow + ln31) * 68;
#pragma unroll
        for (int rg = 0; rg < 4; ++rg) {
            int o0 = ot * 32 + rg * 8 + kg * 4;
            f32x4 bv = *(const f32x4*)(b2l + o0);
            half4_t rv = *(const half4_t*)(rrow + o0);
            half4_t hv;
#pragma unroll
            for (int jj = 0; jj < 4; ++jj)
                hv[jj] = (_Float16)(acc[rg * 4 + jj] + bv[jj] + (float)rv[jj]);
            *(half4_t*)(orow + o0) = hv;
        }
    }
    __syncthreads();

    // copy new trunk chunk out
    _Float16* gout = trunk + (size_t)bn * HT + (size_t)(tc * 64) * H_;
    const _Float16* srow = Xs + 4 * 68;
#pragma unroll
    for (int k2 = 0; k2 < 2; ++k2) {
        int u = k2 * 256 + tid;
        int r = u >> 3, c = u & 7;
        half8_t v = ld_b8(srow + r * 68 + c * 8);
        *(half8_t*)(gout + (size_t)r * H_ + c * 8) = v;
    }
}

// ---------------- conv2(2,LAST): mean-pool partial -> feat; tail blocks = head ----------------
__global__ __launch_bounds__(256, 8) void c2last_k(Args A) {
    __shared__ __align__(16) _Float16 Xs[72 * 68];
    __shared__ __align__(16) _Float16 Rs[64 * 68];
    int blk = blockIdx.x, tid = threadIdx.x;
    if (blk >= 2720) {             // head stream: 8 blocks
        int b = blk - 2720;
        if (tid < 64) {
            int c = tid;
            float w0 = A.head_w[c], w1 = A.head_w[64 + c], w2 = A.head_w[128 + c],
                  w3 = A.head_w[192 + c], w4 = A.head_w[256 + c], w5 = A.head_w[320 + c];
            float bias = A.head_b[c];
            float acc = 0.f;
            for (int t = 0; t < T_; ++t) {
                const float* xr = A.head_pose + ((size_t)b * T_ + t) * HP_;
                float s = fmaf(xr[0], w0, fmaf(xr[1], w1, fmaf(xr[2], w2,
                          fmaf(xr[3], w3, fmaf(xr[4], w4, fmaf(xr[5], w5, bias))))));
                acc += fmaxf(s, 0.f);
            }
            A.feat[(size_t)b * FEAT_DIM + NB_ * H_ + NF_ * H_ + c] = acc * (1.f / 256.f);
        }
        return;
    }
    constexpr int l = L_ - 1;
    bool isB = blk < 4 * B_ * NB_;
    int j = isB ? blk : blk - 4 * B_ * NB_;
    int bn = j >> 2, tc = j & 3;
    const _Float16* G = isB ? A.Gb : A.Gf;
    _Float16* trunk   = isB ? A.TrB : A.TrF;
    const half8_t* w2 = (const half8_t*)(A.W3 + (isB ? 110592 : 331776)) + (size_t)l * (K_ * 8 * H_);
    const float* b2l  = (isB ? A.B2 + 192 : A.B2 + 576) + l * H_;
    int N = isB ? NB_ : NF_;
    int fbase = isB ? 0 : NB_ * H_;

    stage_chunk64(G + (size_t)bn * HT, Xs, tc, tid);
    stage_res64(trunk + (size_t)bn * HT, Rs, tc, tid);
    __syncthreads();

    int ln = tid & 63;
    int w = __builtin_amdgcn_readfirstlane(tid >> 6);
    int ln31 = ln & 31, kg = ln >> 5;
    int ts = w & 1, ot = w >> 1;
    int trow = ts * 32;

    f32x16 acc;
#pragma unroll
    for (int r = 0; r < 16; ++r) acc[r] = 0.f;

    conv_kloop(w2, Xs, trow, ln31, kg, ot, acc);

    // mean-pool partial over this wave's 32 t: per-lane y then shfl over 32 lanes
    float sv[16];
    const _Float16* rrow = Rs + (size_t)(trow + ln31) * 68;
#pragma unroll
    for (int rg = 0; rg < 4; ++rg) {
        int o0 = ot * 32 + rg * 8 + kg * 4;
        f32x4 bv = *(const f32x4*)(b2l + o0);
        half4_t rv = *(const half4_t*)(rrow + o0);
#pragma unroll
        for (int jj = 0; jj < 4; ++jj) {
            int r = rg * 4 + jj;
            float s = acc[r] + bv[jj] + (float)rv[jj];
#pragma unroll
            for (int off = 1; off < 32; off <<= 1) s += __shfl_xor(s, off);
            sv[r] = s;
        }
    }
    __syncthreads();   // Xs reads done; reuse as reduction scratch
    float* red = (float*)Xs;   // [4 waves][32 o-local]
    if (ln31 == 0) {
#pragma unroll
        for (int r = 0; r < 16; ++r) {
            int olocal = (r & 3) + 8 * (r >> 2) + 4 * kg;
            red[w * 32 + olocal] = sv[r];
        }
    }
    __syncthreads();
    if (tid < 64) {
        int o = tid, ot2 = o >> 5, ol = o & 31;
        float s = red[(ot2 * 2) * 32 + ol] + red[(ot2 * 2 + 1) * 32 + ol];
        int b = bn / N, n = bn % N;
        atomicAdd(&A.feat[(size_t)b * FEAT_DIM + fbase + n * H_ + o], s * (1.f / 256.f));
    }
}

// ---------------- fusion layer 1 (5504 -> 256), split-K, all 8 batches per block ----------------
__global__ __launch_bounds__(256) void fus1_k(Args A) {
    __shared__ float fv[8][64];
    int blk = blockIdx.x;          // 86 = 43 ic * 2 khalf
    int ic = blk >> 1, kh = blk & 1;
    int base = ic * 128 + kh * 64;
    int tid = threadIdx.x;
    for (int u = tid; u < 8 * 64; u += 256) {
        int b = u >> 6, j = u & 63;
        fv[b][j] = A.feat[(size_t)b * FEAT_DIM + base + j];
    }
    __syncthreads();
    float acc[8];
#pragma unroll
    for (int b = 0; b < 8; ++b) acc[b] = 0.f;
    const float* wb = A.fus1_w + (size_t)base * 256 + tid;
    for (int i = 0; i < 64; ++i) {
        float wv = wb[(size_t)i * 256];
#pragma unroll
        for (int b = 0; b < 8; ++b) acc[b] = fmaf(fv[b][i], wv, acc[b]);
    }
#pragma unroll
    for (int b = 0; b < 8; ++b) atomicAdd(&A.p1[b * 256 + tid], acc[b]);
}

// ---------------- fusion tail ----------------
__global__ __launch_bounds__(256) void fus_tail_k(Args A) {
    __shared__ float s1[256], s2[128], s3[64];
    int b = blockIdx.x, tid = threadIdx.x;
    s1[tid] = fmaxf(A.p1[b * 256 + tid] + A.fus1_b[tid], 0.f);
    __syncthreads();
    if (tid < 128) {
        float acc = A.fus2_b[tid];
        for (int i = 0; i < 256; ++i) acc = fmaf(s1[i], A.fus2_w[i * 128 + tid], acc);
        s2[tid] = fmaxf(acc, 0.f);
    }
    __syncthreads();
    if (tid < 64) {
        float acc = A.fus3_b[tid];
        for (int i = 0; i < 128; ++i) acc = fmaf(s2[i], A.fus3_w[i * 64 + tid], acc);
        s3[tid] = fmaxf(acc, 0.f);
    }
    __syncthreads();
    if (tid < 5) {
        float acc = A.fus4_b[tid];
        for (int i = 0; i < 64; ++i) acc = fmaf(s3[i], A.fus4_w[i * 5 + tid], acc);
        A.out[b * 5 + tid] = acc;
    }
}

// ---------------- launch ----------------
extern "C" void kernel_launch(void* const* d_in, const int* in_sizes, int n_in,
                              void* d_out, int out_size, void* d_ws, size_t ws_size,
                              hipStream_t stream) {
    float* ws = (float*)d_ws;

    Args A;
    A.body_kps = (const float*)d_in[0];
    A.face_kps = (const float*)d_in[1];
    A.head_pose = (const float*)d_in[2];
    A.body_adj = (const float*)d_in[3];
    A.face_adj = (const float*)d_in[4];
    A.body_pw = (const float*)d_in[5];
    A.body_pb = (const float*)d_in[6];
    A.face_pw = (const float*)d_in[7];
    A.face_pb = (const float*)d_in[8];
    A.head_w = (const float*)d_in[9];
    A.head_b = (const float*)d_in[10];
    A.sb1 = ConvPrepSet{(const float*)d_in[11], (const float*)d_in[12], (const float*)d_in[13],
                        (const float*)d_in[14], (const float*)d_in[15], (const float*)d_in[16]};
    A.b_gcw = (const float*)d_in[17];
    A.b_gcb = (const float*)d_in[18];
    A.sb2 = ConvPrepSet{(const float*)d_in[19], (const float*)d_in[20], (const float*)d_in[21],
                        (const float*)d_in[22], (const float*)d_in[23], (const float*)d_in[24]};
    A.sf1 = ConvPrepSet{(const float*)d_in[25], (const float*)d_in[26], (const float*)d_in[27],
                        (const float*)d_in[28], (const float*)d_in[29], (const float*)d_in[30]};
    A.f_gcw = (const float*)d_in[31];
    A.f_gcb = (const float*)d_in[32];
    A.sf2 = ConvPrepSet{(const float*)d_in[33], (const float*)d_in[34], (const float*)d_in[35],
                        (const float*)d_in[36], (const float*)d_in[37], (const float*)d_in[38]};
    A.fus1_w = (const float*)d_in[39]; A.fus1_b = (const float*)d_in[40];
    A.fus2_w = (const float*)d_in[41]; A.fus2_b = (const float*)d_in[42];
    A.fus3_w = (const float*)d_in[43]; A.fus3_b = (const float*)d_in[44];
    A.fus4_w = (const float*)d_in[45]; A.fus4_b = (const float*)d_in[46];

    A.TrB  = (_Float16*)(ws + OFF_TB);
    A.TrF  = (_Float16*)(ws + OFF_TF);
    A.SupB = (_Float16*)(ws + OFF_SUPB);
    A.SupF = (_Float16*)(ws + OFF_SUPF);
    A.Gb   = (_Float16*)(ws + OFF_GB);
    A.Gf   = (_Float16*)(ws + OFF_GF);
    A.W3   = (_Float16*)(ws + OFF_W3);
    A.GW3  = (_Float16*)(ws + OFF_GW3);
    A.adjPB= (_Float16*)(ws + OFF_ADJPB);
    A.adjPF= (_Float16*)(ws + OFF_ADJPF);
    A.B2   = ws + OFF_B2;
    A.feat = ws + OFF_FEAT;
    A.p1   = ws + OFF_P1;
    A.out  = (float*)d_out;

    const int gconv = 4 * (B_ * NB_ + B_ * NF_);   // 2720 (bn x 4 t-chunks)

    prep_k<<<2038, 256, 0, stream>>>(A);
    projcm_k<<<gconv, 256, 0, stream>>>(A);            // proj + convmix(0)
    for (int l = 0; l < L_; ++l) {
        adjmix_k<<<2048, 256, 0, stream>>>(A, l);
        if (l < L_ - 1) {
            c2_k<<<gconv, 256, 0, stream>>>(A, l);     // conv2(l)
            cm_k<<<gconv, 256, 0, stream>>>(A, l + 1); // convmix(l+1)
        } else {
            c2last_k<<<gconv + 8, 256, 0, stream>>>(A); // conv2(2)+pool + head
        }
    }
    fus1_k<<<86, 256, 0, stream>>>(A);
    fus_tail_k<<<8, 256, 0, stream>>>(A);
}